// Round 14
// baseline (868.268 us; speedup 1.0000x reference)
//
#include <hip/hip_runtime.h>
#include <hip/hip_bf16.h>
#include <stdint.h>

#define DEV __device__ __forceinline__

using bf16x8  = __attribute__((ext_vector_type(8))) __bf16;
using floatx4 = __attribute__((ext_vector_type(4))) float;
using int32x8 = __attribute__((ext_vector_type(8))) int;

constexpr int Bb  = 8;
constexpr int Nn  = 4096;
constexpr int Dd  = 128;
constexpr int Pp  = 256;
constexpr int Kk  = 64;
constexpr int BP  = Bb * Pp;     // 2048
constexpr int M2  = BP * Kk;     // 131072
constexpr float EPSBN = 1e-5f;

DEV unsigned short f2bf(float f) {
  uint32_t u = __float_as_uint(f);
  u += 0x7fffu + ((u >> 16) & 1u);
  return (unsigned short)(u >> 16);
}
DEV float bf2f(unsigned short h) { return __uint_as_float(((uint32_t)h) << 16); }

DEV void async_copy16(const void* g, const void* l) {
  __builtin_amdgcn_global_load_lds(
      (__attribute__((address_space(1))) uint32_t*)(uintptr_t)g,
      (__attribute__((address_space(3))) uint32_t*)(uint32_t)(uintptr_t)l,
      16, 0, 0);
}

// ---------------- prep: fold BN params, zero output scalar ----------------
__global__ void prep_k(const float* g1, const float* be1, const float* m1, const float* v1, const float* cb1,
                       const float* g2, const float* be2, const float* m2, const float* v2, const float* cb2,
                       float* sc1, float* sh1, float* sc2, float* sh2, float* out) {
  int t = threadIdx.x;  // 1024
  float s1 = g1[t] * rsqrtf(v1[t] + EPSBN);
  sc1[t] = s1; sh1[t] = (cb1[t] - m1[t]) * s1 + be1[t];
  float s2 = g2[t] * rsqrtf(v2[t] + EPSBN);
  sc2[t] = s2; sh2[t] = (cb2[t] - m2[t]) * s2 + be2[t];
  if (t == 0) out[0] = 0.f;
}

// ---------------- LDS-tiled transpose fp32[Kd][Nd] -> bf16[n][k] ----------------
__global__ void cvt16(const float* __restrict__ in, unsigned short* __restrict__ out, int Kd, int Nd) {
  __shared__ float ts[32][33];
  int tx = threadIdx.x & 31, ty = threadIdx.x >> 5;
  int n0 = blockIdx.x * 32, k0 = blockIdx.y * 32;
#pragma unroll
  for (int r = 0; r < 4; ++r)
    ts[ty + 8 * r][tx] = in[(size_t)(k0 + ty + 8 * r) * Nd + n0 + tx];
  __syncthreads();
#pragma unroll
  for (int r = 0; r < 4; ++r)
    out[(size_t)(n0 + ty + 8 * r) * Kd + k0 + tx] = f2bf(ts[tx][ty + 8 * r]);
}

// ---------------- LDS-tiled transpose fp32[Kd][Nd] -> fp8 e4m3 [n][k] ----------------
__global__ void cvt8(const float* __restrict__ in, uint8_t* __restrict__ out, int Kd, int Nd) {
  __shared__ float ts[32][33];
  int tx = threadIdx.x & 31, ty = threadIdx.x >> 5;
  int n0 = blockIdx.x * 32, k0 = blockIdx.y * 32;
#pragma unroll
  for (int r = 0; r < 4; ++r)
    ts[ty + 8 * r][tx] = in[(size_t)(k0 + ty + 8 * r) * Nd + n0 + tx];
  __syncthreads();
#pragma unroll
  for (int r = 0; r < 4; ++r) {
    float v = ts[tx][ty + 8 * r];
    int w = __builtin_amdgcn_cvt_pk_fp8_f32(v, v, 0, false);
    out[(size_t)(n0 + ty + 8 * r) * Kd + k0 + tx] = (uint8_t)(w & 0xff);
  }
}

// ---------------- FPS: 4 waves, 16 pts/lane, lean u64 exchange (183us, R10) ----------------
#define DPPF(v, CTRL) __uint_as_float((uint32_t)__builtin_amdgcn_update_dpp( \
    (int)__float_as_uint(v), (int)__float_as_uint(v), CTRL, 0xF, 0xF, false))
#define DPPI(v, CTRL) __builtin_amdgcn_update_dpp(v, v, CTRL, 0xF, 0xF, false)
#define RSTEP2(CTRL) { \
    float od = DPPF(bv, CTRL); \
    int oi = DPPI(bi, CTRL); \
    bool tk = (od > bv) || (od == bv && oi < bi); \
    bv = tk ? od : bv; bi = tk ? oi : bi; }

__global__ __launch_bounds__(256)
void fps_k(const float* __restrict__ xyz, float* __restrict__ pxyz) {
  int b = blockIdx.x, tid = threadIdx.x;
  int lane = tid & 63, wv = tid >> 6;
  __shared__ float xs[Nn], ys[Nn], zs[Nn];   // coord mirror, 48 KB
  __shared__ uint64_t cand[2][4];
  float xr[16], yr[16], zr[16], md[16];
#pragma unroll
  for (int j = 0; j < 16; ++j) {
    int i = tid + j * 256;
    const float* q = &xyz[(size_t)(b * Nn + i) * 3];
    float x = q[0], y = q[1], z = q[2];
    xr[j] = x; yr[j] = y; zr[j] = z; md[j] = 1e10f;
    xs[i] = x; ys[i] = y; zs[i] = z;
  }
  __syncthreads();   // mirror visible to all waves
  const float* q0 = &xyz[(size_t)(b * Nn) * 3];
  float lx = q0[0], ly = q0[1], lz = q0[2];
  if (tid == 0) {
    pxyz[(size_t)(b * Pp) * 3 + 0] = lx;
    pxyz[(size_t)(b * Pp) * 3 + 1] = ly;
    pxyz[(size_t)(b * Pp) * 3 + 2] = lz;
  }
  for (int p = 1; p < Pp; ++p) {
    float bv = -1.f; int bi = 0x7fffffff;
#pragma unroll
    for (int j = 0; j < 16; ++j) {
      // no-fma arithmetic to match numpy (x-l)^2 sum bit pattern
      float dx = __fadd_rn(xr[j], -lx);
      float dy = __fadd_rn(yr[j], -ly);
      float dz = __fadd_rn(zr[j], -lz);
      float d = __fadd_rn(__fadd_rn(__fmul_rn(dx, dx), __fmul_rn(dy, dy)), __fmul_rn(dz, dz));
      float m = fminf(md[j], d);
      md[j] = m;
      if (m > bv) { bv = m; bi = tid + j * 256; }   // strict >: lowest idx on tie
    }
    // DPP wave64 argmax (d,idx) -> lane 63
    RSTEP2(0x111) RSTEP2(0x112) RSTEP2(0x114) RSTEP2(0x118) RSTEP2(0x142) RSTEP2(0x143)
    int s = p & 1;
    if (lane == 63)
      cand[s][wv] = ((uint64_t)(uint32_t)__float_as_uint(bv) << 32) |
                    (uint32_t)(0x7fffffff - bi);
    __syncthreads();
    uint64_t k0 = cand[s][0], k1 = cand[s][1], k2 = cand[s][2], k3 = cand[s][3];
    uint64_t ka = (k0 > k1) ? k0 : k1;
    uint64_t kb = (k2 > k3) ? k2 : k3;
    uint64_t kw = (ka > kb) ? ka : kb;
    int wi = 0x7fffffff - (int)(uint32_t)(kw & 0xffffffffu);
    lx = xs[wi]; ly = ys[wi]; lz = zs[wi];   // broadcast reads
    if (tid == 0) {
      pxyz[(size_t)(b * Pp + p) * 3 + 0] = lx;
      pxyz[(size_t)(b * Pp + p) * 3 + 1] = ly;
      pxyz[(size_t)(b * Pp + p) * 3 + 2] = lz;
    }
  }
}

// ---------------- grouping: 64-NN radix select + feat maxpool + gxyz ----------------
__global__ __launch_bounds__(256)
void group_k(const float* __restrict__ xyz, const float* __restrict__ feat,
             const float* __restrict__ pxyz, unsigned short* __restrict__ pfb,
             float* __restrict__ gxyz) {
  int bp = blockIdx.x, tid = threadIdx.x;
  int b = bp >> 8;
  __shared__ uint32_t dbits[Nn];
  __shared__ uint32_t hist[256];
  __shared__ int sel[64];
  __shared__ uint32_t svDigit, svWant, svClt, svCeq;
  __shared__ float red[256];
  float px = pxyz[(size_t)bp * 3], py = pxyz[(size_t)bp * 3 + 1], pz = pxyz[(size_t)bp * 3 + 2];
  for (int i = tid; i < Nn; i += 256) {
    const float* q = &xyz[(size_t)(b * Nn + i) * 3];
    float dx = q[0] - px, dy = q[1] - py, dz = q[2] - pz;
    dbits[i] = __float_as_uint(dx * dx + dy * dy + dz * dz);
  }
  uint32_t prefix = 0, want = 64;
  for (int shift = 24; shift >= 0; shift -= 8) {
    __syncthreads();
    hist[tid] = 0;
    __syncthreads();
    for (int i = tid; i < Nn; i += 256) {
      uint32_t v = dbits[i];
      bool match = (shift == 24) || ((v >> (shift + 8)) == prefix);
      if (match) atomicAdd(&hist[(v >> shift) & 255], 1u);
    }
    __syncthreads();
    uint32_t myh = hist[tid];
    for (int off = 1; off < 256; off <<= 1) {
      uint32_t o = (tid >= off) ? hist[tid - off] : 0u;
      __syncthreads();
      hist[tid] += o;
      __syncthreads();
    }
    uint32_t cum = hist[tid];
    uint32_t prev = cum - myh;
    if (prev < want && want <= cum) { svDigit = (uint32_t)tid; svWant = want - prev; }
    __syncthreads();
    prefix = (prefix << 8) | svDigit;
    want = svWant;
  }
  uint32_t tval = prefix;
  if (tid == 0) { svClt = 0; svCeq = 0; }
  __syncthreads();
  for (int i = tid; i < Nn; i += 256) {
    if (dbits[i] < tval) { uint32_t pos = atomicAdd(&svClt, 1u); sel[pos] = i; }
  }
  __syncthreads();
  uint32_t clt = svClt;
  for (int i = tid; i < Nn; i += 256) {
    if (dbits[i] == tval) {
      uint32_t pos = atomicAdd(&svCeq, 1u);
      if (clt + pos < 64) sel[clt + pos] = i;
    }
  }
  __syncthreads();
  if (tid < 192) {
    int k = tid / 3, c = tid - k * 3;
    float sub = (c == 0) ? px : (c == 1) ? py : pz;
    gxyz[(size_t)bp * 192 + tid] = xyz[(size_t)(b * Nn + sel[k]) * 3 + c] - sub;
  }
  int dch = tid & 127, half = tid >> 7;
  float m = -1e30f;
  for (int k = half * 32; k < half * 32 + 32; ++k)
    m = fmaxf(m, feat[(size_t)(b * Nn + sel[k]) * Dd + dch]);
  red[tid] = m;
  __syncthreads();
  if (half == 0) pfb[(size_t)bp * Dd + dch] = f2bf(fmaxf(m, red[tid + 128]));
}

// ---------------- bf16 MFMA GEMM: C[M,N] = A[M,K] * Bt[N,K]^T ----------------
template <int EPI>
__global__ __launch_bounds__(256)
void gemm_bt(const unsigned short* __restrict__ A, const unsigned short* __restrict__ Bt,
             float* __restrict__ Cf, unsigned short* __restrict__ Ch,
             const float* __restrict__ p0,
             int Npar, int Kd, int nbn) {
  __shared__ __align__(16) unsigned short As[128 * 32];
  __shared__ __align__(16) unsigned short Bs[128 * 32];
  const int tid = threadIdx.x;
  const int lane = tid & 63, wid = tid >> 6;
  const int bn = blockIdx.x % nbn, bm = blockIdx.x / nbn;
  const int m0 = bm * 128, n0 = bn * 128;
  const int quad = lane >> 4, l15 = lane & 15;
  const int wm = wid & 1, wn = wid >> 1;

  floatx4 acc[4][4];
#pragma unroll
  for (int i = 0; i < 4; ++i)
#pragma unroll
    for (int j = 0; j < 4; ++j) acc[i][j] = floatx4{0.f, 0.f, 0.f, 0.f};

  const int c0i = tid, c1i = tid + 256;
  const int r0 = c0i >> 2, o0 = (c0i & 3) * 8;
  const int r1 = c1i >> 2, o1 = (c1i & 3) * 8;

  for (int k0 = 0; k0 < Kd; k0 += 32) {
    async_copy16(A + (size_t)(m0 + r0) * Kd + k0 + o0, &As[c0i * 8]);
    async_copy16(A + (size_t)(m0 + r1) * Kd + k0 + o1, &As[c1i * 8]);
    async_copy16(Bt + (size_t)(n0 + r0) * Kd + k0 + o0, &Bs[c0i * 8]);
    async_copy16(Bt + (size_t)(n0 + r1) * Kd + k0 + o1, &Bs[c1i * 8]);
    __syncthreads();
    const bf16x8* Ap = reinterpret_cast<const bf16x8*>(As);
    const bf16x8* Bp = reinterpret_cast<const bf16x8*>(Bs);
    bf16x8 af[4], bfv[4];
#pragma unroll
    for (int t = 0; t < 4; ++t) {
      af[t]  = Ap[(wm * 64 + t * 16 + l15) * 4 + quad];
      bfv[t] = Bp[(wn * 64 + t * 16 + l15) * 4 + quad];
    }
#pragma unroll
    for (int mt = 0; mt < 4; ++mt)
#pragma unroll
      for (int nt = 0; nt < 4; ++nt)
        acc[mt][nt] = __builtin_amdgcn_mfma_f32_16x16x32_bf16(af[mt], bfv[nt], acc[mt][nt], 0, 0, 0);
    __syncthreads();
  }

  const int rowBase = m0 + wm * 64 + quad * 4;
  const int colBase = n0 + wn * 64 + l15;

  if (EPI == 0) {
#pragma unroll
    for (int mt = 0; mt < 4; ++mt)
#pragma unroll
      for (int nt = 0; nt < 4; ++nt)
#pragma unroll
        for (int r = 0; r < 4; ++r)
          Cf[(size_t)(rowBase + mt * 16 + r) * Npar + colBase + nt * 16] = acc[mt][nt][r];
  } else {
#pragma unroll
    for (int nt = 0; nt < 4; ++nt) {
      float bias = p0[colBase + nt * 16];
#pragma unroll
      for (int mt = 0; mt < 4; ++mt)
#pragma unroll
        for (int r = 0; r < 4; ++r) {
          float v = fmaxf(acc[mt][nt][r] + bias, 0.f);
          Ch[(size_t)(rowBase + mt * 16 + r) * Npar + colBase + nt * 16] = f2bf(v);
        }
    }
  }
}

// ---------------- conv2 MX-fp8, h1 FUSED, 128-row M-tile, 160KB LDS ----------------
// R13: fusion killed FETCH (532->13MB) but 32-row tiles 4x'd staged-B bytes
// (4.3GB @ ~14TB/s == 298us). This version: A-slab 128x1024 fp8 (128KB LDS,
// built in-kernel), double-buffered 16KB B tiles (2x16KB) = 160KB total.
// Staged bytes = B only = 1024 blocks x 1MB = 1.07GB. 1 block/CU; staging
// latency hidden by software dbuf (prefetch it+1 before computing it).
// fsum aliases B buf0 after the final barrier.
__global__ __launch_bounds__(256, 1)
void gemm_mx3(const float* __restrict__ u1, const float* __restrict__ cw1,
              const float* __restrict__ coarse, const float* __restrict__ sc1,
              const float* __restrict__ sh1,
              const uint8_t* __restrict__ Bt,
              const float* __restrict__ p0, const float* __restrict__ p1,
              const float* __restrict__ cw3, const float* __restrict__ cb3,
              float* __restrict__ fine) {
  __shared__ __align__(128) uint8_t As[128 * 1024];    // 128 KB
  __shared__ __align__(128) uint8_t Bs[2][128 * 128];  // 2 x 16 KB
  const int tid = threadIdx.x;
  const int lane = tid & 63, wid = tid >> 6;
  const int bm = blockIdx.x;                 // 1024 blocks
  const int quad = lane >> 4, l15 = lane & 15;
  const int wm = wid & 1, wn = wid >> 1;
  const int bp0 = bm * 2;                    // two patches per block

  // stage tile helper (16B-chunk XOR swizzle, R12-identical)
  auto stageB = [&](int it, uint8_t* buf) {
    int n0 = (it >> 3) * 128, k0 = (it & 7) * 128;
#pragma unroll
    for (int c = 0; c < 4; ++c) {
      int ci = c * 256 + tid;
      int row = ci >> 3, cp = ci & 7;
      int cc = cp ^ (row & 7);
      async_copy16(Bt + (size_t)(n0 + row) * 1024 + k0 + cc * 16, &buf[ci * 16]);
    }
  };

  // issue tile 0 prefetch immediately (into buf0)
  stageB(0, Bs[0]);
  // co mirror in buf1 (consumed during A-build, before tile1 prefetch)
  float* coLds = (float*)Bs[1];
  if (tid < 96) coLds[tid] = coarse[(size_t)bp0 * 48 + tid];
  __syncthreads();

  // ---- build A-slab: thread owns cols [4t,4t+4), 128 rows ----
  {
    int n0c = tid * 4;
    float4 un0 = *(const float4*)&u1[(size_t)bp0 * 1024 + n0c];
    float4 un1 = *(const float4*)&u1[(size_t)(bp0 + 1) * 1024 + n0c];
    float4 a0  = *(const float4*)&cw1[128 * 1024 + n0c];
    float4 a1  = *(const float4*)&cw1[129 * 1024 + n0c];
    float4 b0  = *(const float4*)&cw1[130 * 1024 + n0c];
    float4 b1v = *(const float4*)&cw1[131 * 1024 + n0c];
    float4 b2v = *(const float4*)&cw1[132 * 1024 + n0c];
    float4 sc  = *(const float4*)&sc1[n0c];
    float4 sh  = *(const float4*)&sh1[n0c];
    const float sxv[4] = {-0.05f, 0.05f, -0.05f, 0.05f};
    const float syv[4] = {-0.05f, -0.05f, 0.05f, 0.05f};
    uint32_t* Aw = (uint32_t*)As;
    int gc = tid >> 2, dw = tid & 3;
    float t0 = 0.f, t1 = 0.f, t2 = 0.f, t3 = 0.f;
    for (int row = 0; row < 128; ++row) {
      int h = row >> 6;
      if ((row & 3) == 0) {
        int j = (row & 63) >> 2;
        float c0 = coLds[h * 48 + j * 3 + 0];
        float c1 = coLds[h * 48 + j * 3 + 1];
        float c2 = coLds[h * 48 + j * 3 + 2];
        t0 = c0 * b0.x + c1 * b1v.x + c2 * b2v.x;
        t1 = c0 * b0.y + c1 * b1v.y + c2 * b2v.y;
        t2 = c0 * b0.z + c1 * b1v.z + c2 * b2v.z;
        t3 = c0 * b0.w + c1 * b1v.w + c2 * b2v.w;
      }
      float sx = sxv[row & 3], sy = syv[row & 3];
      float4 un = h ? un1 : un0;
      float x0 = un.x + sx * a0.x + sy * a1.x + t0;
      float x1 = un.y + sx * a0.y + sy * a1.y + t1;
      float x2 = un.z + sx * a0.z + sy * a1.z + t2;
      float x3 = un.w + sx * a0.w + sy * a1.w + t3;
      float v0 = fmaxf(x0 * sc.x + sh.x, 0.f);
      float v1 = fmaxf(x1 * sc.y + sh.y, 0.f);
      float v2 = fmaxf(x2 * sc.z + sh.z, 0.f);
      float v3 = fmaxf(x3 * sc.w + sh.w, 0.f);
      int w = __builtin_amdgcn_cvt_pk_fp8_f32(v0, v1, 0, false);
      w = __builtin_amdgcn_cvt_pk_fp8_f32(v2, v3, w, true);
      int phys = (gc & ~7) | ((gc & 7) ^ (row & 7));
      Aw[row * 256 + phys * 4 + dw] = (uint32_t)w;
    }
  }
  float fp[4][4][3];
#pragma unroll
  for (int mt = 0; mt < 4; ++mt)
#pragma unroll
    for (int r = 0; r < 4; ++r)
      fp[mt][r][0] = fp[mt][r][1] = fp[mt][r][2] = 0.f;

  const uint4* Ap = (const uint4*)As;
  int it = 0;
  for (int bn = 0; bn < 8; ++bn) {
    floatx4 acc[4][4];
#pragma unroll
    for (int i = 0; i < 4; ++i)
#pragma unroll
      for (int j = 0; j < 4; ++j) acc[i][j] = floatx4{0.f, 0.f, 0.f, 0.f};

    for (int k0i = 0; k0i < 8; ++k0i) {
      __syncthreads();                       // tile `it` ready; prev compute done
      if (it + 1 < 64) stageB(it + 1, Bs[(it + 1) & 1]);
      const uint4* Bp = (const uint4*)Bs[it & 1];
      int kc = k0i * 8;                      // A base 16B-chunk (mult of 8)
      int32x8 av[4], bv[4];
#pragma unroll
      for (int t = 0; t < 4; ++t) {
        int rm = wm * 64 + t * 16 + l15;
        int swm = rm & 7;
        uint4 alo = Ap[rm * 64 + kc + ((2 * quad) ^ swm)];
        uint4 ahi = Ap[rm * 64 + kc + ((2 * quad + 1) ^ swm)];
        int rn = wn * 64 + t * 16 + l15;
        int swn = rn & 7;
        uint4 blo = Bp[rn * 8 + ((2 * quad) ^ swn)];
        uint4 bhi = Bp[rn * 8 + ((2 * quad + 1) ^ swn)];
        av[t] = int32x8{(int)alo.x, (int)alo.y, (int)alo.z, (int)alo.w,
                        (int)ahi.x, (int)ahi.y, (int)ahi.z, (int)ahi.w};
        bv[t] = int32x8{(int)blo.x, (int)blo.y, (int)blo.z, (int)blo.w,
                        (int)bhi.x, (int)bhi.y, (int)bhi.z, (int)bhi.w};
      }
#pragma unroll
      for (int mt = 0; mt < 4; ++mt)
#pragma unroll
        for (int nt = 0; nt < 4; ++nt)
          acc[mt][nt] = __builtin_amdgcn_mfma_scale_f32_16x16x128_f8f6f4(
              av[mt], bv[nt], acc[mt][nt], 0, 0, 0, 127, 0, 127);
      ++it;
    }

    const int n0 = bn * 128;
#pragma unroll
    for (int nt = 0; nt < 4; ++nt) {
      int col = n0 + wn * 64 + nt * 16 + l15;
      float sc = p0[col], sh = p1[col];
      float c0 = cw3[col * 3], c1 = cw3[col * 3 + 1], c2 = cw3[col * 3 + 2];
#pragma unroll
      for (int mt = 0; mt < 4; ++mt)
#pragma unroll
        for (int r = 0; r < 4; ++r) {
          float v = fmaxf(acc[mt][nt][r] * sc + sh, 0.f);
          fp[mt][r][0] += v * c0; fp[mt][r][1] += v * c1; fp[mt][r][2] += v * c2;
        }
    }
  }

#pragma unroll
  for (int off = 1; off < 16; off <<= 1)
#pragma unroll
    for (int mt = 0; mt < 4; ++mt)
#pragma unroll
      for (int r = 0; r < 4; ++r)
#pragma unroll
        for (int i = 0; i < 3; ++i)
          fp[mt][r][i] += __shfl_xor(fp[mt][r][i], off, 64);
  __syncthreads();                           // Bs fully consumed -> alias fsum
  float* fs = (float*)Bs[0];                 // [ (wm*2+wn)*64 + rowLocal ][3]
  if (l15 == 0) {
#pragma unroll
    for (int mt = 0; mt < 4; ++mt)
#pragma unroll
      for (int r = 0; r < 4; ++r) {
        int rowLocal = mt * 16 + quad * 4 + r;
#pragma unroll
        for (int i = 0; i < 3; ++i)
          fs[((wm * 2 + wn) * 64 + rowLocal) * 3 + i] = fp[mt][r][i];
      }
  }
  __syncthreads();
  for (int t = tid; t < 128 * 3; t += 256) {
    int row = t / 3, i = t - row * 3;
    int h = row >> 6, rl = row & 63;
    float s = fs[((h * 2 + 0) * 64 + rl) * 3 + i] + fs[((h * 2 + 1) * 64 + rl) * 3 + i];
    int g = bm * 128 + row;
    int bp = bp0 + h, j = rl >> 2;
    fine[(size_t)g * 3 + i] = s + cb3[i] + coarse[(size_t)bp * 48 + j * 3 + i];
  }
}

// ---------------- coarse = h2m @ w3 + b3 (fp32, thin N=48) ----------------
__global__ __launch_bounds__(256)
void coarse_k(const unsigned short* __restrict__ h2m, const float* __restrict__ w3,
              const float* __restrict__ b3, float* __restrict__ coarse) {
  int r = blockIdx.x, tid = threadIdx.x;
  __shared__ float hrow[1024];
  __shared__ float part[192];
  for (int i = tid; i < 1024; i += 256) hrow[i] = bf2f(h2m[(size_t)r * 1024 + i]);
  __syncthreads();
  if (tid < 192) {
    int j = tid % 48, seg = tid / 48;
    float acc = 0.f;
    for (int k = seg * 256; k < seg * 256 + 256; ++k) acc += hrow[k] * w3[(size_t)k * 48 + j];
    part[tid] = acc;
  }
  __syncthreads();
  if (tid < 48)
    coarse[(size_t)r * 48 + tid] = part[tid] + part[tid + 48] + part[tid + 96] + part[tid + 144] + b3[tid];
}

// ---------------- chamfer: one wave per patch ----------------
__global__ __launch_bounds__(256)
void chamfer_k(const float* __restrict__ fine, const float* __restrict__ gxyz,
               float* __restrict__ out) {
  int tid = threadIdx.x, wv = tid >> 6, lane = tid & 63;
  int bp = blockIdx.x * 4 + wv;
  __shared__ float sf[4][64][3], sg[4][64][3];
  const float* fr = &fine[(size_t)(bp * 64 + lane) * 3];
  const float* gr = &gxyz[(size_t)(bp * 64 + lane) * 3];
  sf[wv][lane][0] = fr[0]; sf[wv][lane][1] = fr[1]; sf[wv][lane][2] = fr[2];
  sg[wv][lane][0] = gr[0]; sg[wv][lane][1] = gr[1]; sg[wv][lane][2] = gr[2];
  __syncthreads();
  float f0 = sf[wv][lane][0], f1 = sf[wv][lane][1], f2 = sf[wv][lane][2];
  float g0 = sg[wv][lane][0], g1 = sg[wv][lane][1], g2 = sg[wv][lane][2];
  float rmin = 1e30f, cmin = 1e30f;
  for (int j = 0; j < 64; ++j) {
    float dx = f0 - sg[wv][j][0], dy = f1 - sg[wv][j][1], dz = f2 - sg[wv][j][2];
    rmin = fminf(rmin, dx * dx + dy * dy + dz * dz);
    float ex = sf[wv][j][0] - g0, ey = sf[wv][j][1] - g1, ez = sf[wv][j][2] - g2;
    cmin = fminf(cmin, ex * ex + ey * ey + ez * ez);
  }
  float tot = rmin + cmin;
  for (int off = 32; off; off >>= 1) tot += __shfl_down(tot, off, 64);
  if (lane == 0) atomicAdd(out, tot * (1.0f / 131072.0f));
}

extern "C" void kernel_launch(void* const* d_in, const int* in_sizes, int n_in,
                              void* d_out, int out_size, void* d_ws, size_t ws_size,
                              hipStream_t stream) {
  (void)in_sizes; (void)n_in; (void)out_size; (void)ws_size;
  const float* xyz = (const float*)d_in[0];
  const float* feat = (const float*)d_in[1];
  const float* w1 = (const float*)d_in[2];
  const float* b1 = (const float*)d_in[3];
  const float* w2 = (const float*)d_in[4];
  const float* b2 = (const float*)d_in[5];
  const float* w3 = (const float*)d_in[6];
  const float* b3 = (const float*)d_in[7];
  const float* cw1 = (const float*)d_in[8];
  const float* cb1 = (const float*)d_in[9];
  const float* g1 = (const float*)d_in[10];
  const float* be1 = (const float*)d_in[11];
  const float* m1 = (const float*)d_in[12];
  const float* v1 = (const float*)d_in[13];
  const float* cw2 = (const float*)d_in[14];
  const float* cb2 = (const float*)d_in[15];
  const float* g2 = (const float*)d_in[16];
  const float* be2 = (const float*)d_in[17];
  const float* m2 = (const float*)d_in[18];
  const float* v2 = (const float*)d_in[19];
  const float* cw3 = (const float*)d_in[20];
  const float* cb3 = (const float*)d_in[21];
  float* out = (float*)d_out;

  uint8_t* ws = (uint8_t*)d_ws;
  size_t off = 0;
  auto alloc = [&](size_t bytes) {
    void* p = ws + off;
    off = (off + bytes + 255) & ~(size_t)255;
    return p;
  };
  float*          pxyz  = (float*)alloc((size_t)BP * 3 * 4);
  unsigned short* w1t   = (unsigned short*)alloc((size_t)1024 * 128 * 2);
  unsigned short* cw1t  = (unsigned short*)alloc((size_t)1024 * 128 * 2);
  unsigned short* w2t   = (unsigned short*)alloc((size_t)1024 * 1024 * 2);
  uint8_t*        cw2t8 = (uint8_t*)alloc((size_t)1024 * 1024);
  float*          sc1   = (float*)alloc(4096);
  float*          sh1   = (float*)alloc(4096);
  float*          sc2   = (float*)alloc(4096);
  float*          sh2   = (float*)alloc(4096);
  unsigned short* pfb   = (unsigned short*)alloc((size_t)BP * 128 * 2);
  float*          gxyz  = (float*)alloc((size_t)BP * 64 * 3 * 4);
  float*          u1    = (float*)alloc((size_t)BP * 1024 * 4);
  unsigned short* hb    = (unsigned short*)alloc((size_t)BP * 1024 * 2);
  unsigned short* h2m   = (unsigned short*)alloc((size_t)BP * 1024 * 2);
  float*          coarse = (float*)alloc((size_t)BP * 48 * 4);
  float*          fine  = (float*)alloc((size_t)M2 * 3 * 4);

  prep_k<<<1, 1024, 0, stream>>>(g1, be1, m1, v1, cb1, g2, be2, m2, v2, cb2,
                                 sc1, sh1, sc2, sh2, out);
  cvt16<<<dim3(1024 / 32, 128 / 32), 256, 0, stream>>>(w1, w1t, 128, 1024);
  cvt16<<<dim3(1024 / 32, 128 / 32), 256, 0, stream>>>(cw1, cw1t, 128, 1024);
  cvt16<<<dim3(1024 / 32, 1024 / 32), 256, 0, stream>>>(w2, w2t, 1024, 1024);
  cvt8<<<dim3(1024 / 32, 1024 / 32), 256, 0, stream>>>(cw2, cw2t8, 1024, 1024);
  fps_k<<<Bb, 256, 0, stream>>>(xyz, pxyz);
  group_k<<<BP, 256, 0, stream>>>(xyz, feat, pxyz, pfb, gxyz);
  // u1 = pf @ cw1[:128]   (fp32 out)
  gemm_bt<0><<<(2048 / 128) * 8, 256, 0, stream>>>(pfb, cw1t, u1, nullptr, nullptr,
                                                   1024, 128, 8);
  // h = relu(pf @ w1 + b1)
  gemm_bt<1><<<(2048 / 128) * 8, 256, 0, stream>>>(pfb, w1t, nullptr, hb, b1,
                                                   1024, 128, 8);
  // h2m = relu(h @ w2 + b2)
  gemm_bt<1><<<(2048 / 128) * 8, 256, 0, stream>>>(hb, w2t, nullptr, h2m, b2,
                                                   1024, 1024, 8);
  coarse_k<<<2048, 256, 0, stream>>>(h2m, w3, b3, coarse);
  // conv2 MX-fp8, h1 fused, 128-row tiles, 160KB LDS
  gemm_mx3<<<M2 / 128, 256, 0, stream>>>(u1, cw1, coarse, sc1, sh1,
                                         cw2t8, sc2, sh2, cw3, cb3, fine);
  chamfer_k<<<BP / 4, 256, 0, stream>>>(fine, gxyz, out);
}

// Round 15
// 629.509 us; speedup vs baseline: 1.3793x; 1.3793x over previous
//
#include <hip/hip_runtime.h>
#include <hip/hip_bf16.h>
#include <stdint.h>

#define DEV __device__ __forceinline__

using bf16x8  = __attribute__((ext_vector_type(8))) __bf16;
using floatx4 = __attribute__((ext_vector_type(4))) float;
using int32x8 = __attribute__((ext_vector_type(8))) int;

constexpr int Bb  = 8;
constexpr int Nn  = 4096;
constexpr int Dd  = 128;
constexpr int Pp  = 256;
constexpr int Kk  = 64;
constexpr int BP  = Bb * Pp;     // 2048
constexpr int M2  = BP * Kk;     // 131072
constexpr float EPSBN = 1e-5f;

DEV unsigned short f2bf(float f) {
  uint32_t u = __float_as_uint(f);
  u += 0x7fffu + ((u >> 16) & 1u);
  return (unsigned short)(u >> 16);
}
DEV float bf2f(unsigned short h) { return __uint_as_float(((uint32_t)h) << 16); }

DEV void async_copy16(const void* g, const void* l) {
  __builtin_amdgcn_global_load_lds(
      (__attribute__((address_space(1))) uint32_t*)(uintptr_t)g,
      (__attribute__((address_space(3))) uint32_t*)(uint32_t)(uintptr_t)l,
      16, 0, 0);
}

// ================= setup_k: heterogeneous prologue, one launch =================
// blocks 0..7:      FPS (one per batch; 4 waves, 16 pts/lane, u64 exchange)
// block  8:         BN-fold prep + out zero
// blocks 9..136:    w1  fp32[128,1024]  -> bf16 w1t [n][k]
// blocks 137..264:  cw1 fp32[128,1024]  -> bf16 cw1t[n][k]
// blocks 265..1288: w2  fp32[1024,1024] -> bf16 w2t [n][k]
// blocks 1289..2312:cw2 fp32[1024,1024] -> fp8  cw2t8[n][k]
// Transposes run on idle CUs in FPS's 183us shadow.
#define DPPF(v, CTRL) __uint_as_float((uint32_t)__builtin_amdgcn_update_dpp( \
    (int)__float_as_uint(v), (int)__float_as_uint(v), CTRL, 0xF, 0xF, false))
#define DPPI(v, CTRL) __builtin_amdgcn_update_dpp(v, v, CTRL, 0xF, 0xF, false)
#define RSTEP2(CTRL) { \
    float od = DPPF(bv, CTRL); \
    int oi = DPPI(bi, CTRL); \
    bool tk = (od > bv) || (od == bv && oi < bi); \
    bv = tk ? od : bv; bi = tk ? oi : bi; }

__global__ __launch_bounds__(256)
void setup_k(const float* __restrict__ xyz, float* __restrict__ pxyz,
             const float* __restrict__ g1, const float* __restrict__ be1,
             const float* __restrict__ m1, const float* __restrict__ v1,
             const float* __restrict__ cb1,
             const float* __restrict__ g2, const float* __restrict__ be2,
             const float* __restrict__ m2, const float* __restrict__ v2,
             const float* __restrict__ cb2,
             float* __restrict__ sc1, float* __restrict__ sh1,
             float* __restrict__ sc2, float* __restrict__ sh2, float* __restrict__ out,
             const float* __restrict__ w1, unsigned short* __restrict__ w1t,
             const float* __restrict__ cw1, unsigned short* __restrict__ cw1t,
             const float* __restrict__ w2, unsigned short* __restrict__ w2t,
             const float* __restrict__ cw2, uint8_t* __restrict__ cw2t8) {
  __shared__ float sbuf[3 * Nn + 16];     // fps mirror OR transpose tile
  const int blk = blockIdx.x, tid = threadIdx.x;

  if (blk < 8) {
    // ---------------- FPS ----------------
    int b = blk;
    int lane = tid & 63, wv = tid >> 6;
    float* xs = sbuf;
    float* ys = sbuf + Nn;
    float* zs = sbuf + 2 * Nn;
    uint64_t* cand = (uint64_t*)(sbuf + 3 * Nn);  // 2x4 slots
    float xr[16], yr[16], zr[16], md[16];
#pragma unroll
    for (int j = 0; j < 16; ++j) {
      int i = tid + j * 256;
      const float* q = &xyz[(size_t)(b * Nn + i) * 3];
      float x = q[0], y = q[1], z = q[2];
      xr[j] = x; yr[j] = y; zr[j] = z; md[j] = 1e10f;
      xs[i] = x; ys[i] = y; zs[i] = z;
    }
    __syncthreads();
    const float* q0 = &xyz[(size_t)(b * Nn) * 3];
    float lx = q0[0], ly = q0[1], lz = q0[2];
    if (tid == 0) {
      pxyz[(size_t)(b * Pp) * 3 + 0] = lx;
      pxyz[(size_t)(b * Pp) * 3 + 1] = ly;
      pxyz[(size_t)(b * Pp) * 3 + 2] = lz;
    }
    for (int p = 1; p < Pp; ++p) {
      float bv = -1.f; int bi = 0x7fffffff;
#pragma unroll
      for (int j = 0; j < 16; ++j) {
        // no-fma arithmetic to match numpy (x-l)^2 sum bit pattern
        float dx = __fadd_rn(xr[j], -lx);
        float dy = __fadd_rn(yr[j], -ly);
        float dz = __fadd_rn(zr[j], -lz);
        float d = __fadd_rn(__fadd_rn(__fmul_rn(dx, dx), __fmul_rn(dy, dy)), __fmul_rn(dz, dz));
        float m = fminf(md[j], d);
        md[j] = m;
        if (m > bv) { bv = m; bi = tid + j * 256; }  // strict >: lowest idx on tie
      }
      RSTEP2(0x111) RSTEP2(0x112) RSTEP2(0x114) RSTEP2(0x118) RSTEP2(0x142) RSTEP2(0x143)
      int s = p & 1;
      if (lane == 63)
        cand[s * 4 + wv] = ((uint64_t)(uint32_t)__float_as_uint(bv) << 32) |
                           (uint32_t)(0x7fffffff - bi);
      __syncthreads();
      uint64_t k0 = cand[s * 4 + 0], k1 = cand[s * 4 + 1];
      uint64_t k2 = cand[s * 4 + 2], k3 = cand[s * 4 + 3];
      uint64_t ka = (k0 > k1) ? k0 : k1;
      uint64_t kb = (k2 > k3) ? k2 : k3;
      uint64_t kw = (ka > kb) ? ka : kb;
      int wi = 0x7fffffff - (int)(uint32_t)(kw & 0xffffffffu);
      lx = xs[wi]; ly = ys[wi]; lz = zs[wi];
      if (tid == 0) {
        pxyz[(size_t)(b * Pp + p) * 3 + 0] = lx;
        pxyz[(size_t)(b * Pp + p) * 3 + 1] = ly;
        pxyz[(size_t)(b * Pp + p) * 3 + 2] = lz;
      }
    }
    return;
  }
  if (blk == 8) {
    // ---------------- prep ----------------
    for (int t = tid; t < 1024; t += 256) {
      float s1 = g1[t] * rsqrtf(v1[t] + EPSBN);
      sc1[t] = s1; sh1[t] = (cb1[t] - m1[t]) * s1 + be1[t];
      float s2 = g2[t] * rsqrtf(v2[t] + EPSBN);
      sc2[t] = s2; sh2[t] = (cb2[t] - m2[t]) * s2 + be2[t];
    }
    if (tid == 0) out[0] = 0.f;
    return;
  }
  // ---------------- transposes (32x32 LDS tile, +1 pad) ----------------
  const float* in; int Kd, Nd, t; bool to8 = false;
  unsigned short* o16 = nullptr; uint8_t* o8 = nullptr;
  if (blk < 137)       { in = w1;  o16 = w1t;  Kd = 128;  Nd = 1024; t = blk - 9; }
  else if (blk < 265)  { in = cw1; o16 = cw1t; Kd = 128;  Nd = 1024; t = blk - 137; }
  else if (blk < 1289) { in = w2;  o16 = w2t;  Kd = 1024; Nd = 1024; t = blk - 265; }
  else                 { in = cw2; o8 = cw2t8; Kd = 1024; Nd = 1024; t = blk - 1289; to8 = true; }
  float (*ts)[33] = (float(*)[33])sbuf;
  int tx = tid & 31, ty = tid >> 5;
  int n0 = (t & 31) * 32, k0 = (t >> 5) * 32;
#pragma unroll
  for (int r = 0; r < 4; ++r)
    ts[ty + 8 * r][tx] = in[(size_t)(k0 + ty + 8 * r) * Nd + n0 + tx];
  __syncthreads();
#pragma unroll
  for (int r = 0; r < 4; ++r) {
    float v = ts[tx][ty + 8 * r];
    if (to8) {
      int w = __builtin_amdgcn_cvt_pk_fp8_f32(v, v, 0, false);
      o8[(size_t)(n0 + ty + 8 * r) * Kd + k0 + tx] = (uint8_t)(w & 0xff);
    } else {
      o16[(size_t)(n0 + ty + 8 * r) * Kd + k0 + tx] = f2bf(v);
    }
  }
}

// ---------------- grouping: 64-NN radix select + feat maxpool + gxyz ----------------
__global__ __launch_bounds__(256)
void group_k(const float* __restrict__ xyz, const float* __restrict__ feat,
             const float* __restrict__ pxyz, unsigned short* __restrict__ pfb,
             float* __restrict__ gxyz) {
  int bp = blockIdx.x, tid = threadIdx.x;
  int b = bp >> 8;
  __shared__ uint32_t dbits[Nn];
  __shared__ uint32_t hist[256];
  __shared__ int sel[64];
  __shared__ uint32_t svDigit, svWant, svClt, svCeq;
  __shared__ float red[256];
  float px = pxyz[(size_t)bp * 3], py = pxyz[(size_t)bp * 3 + 1], pz = pxyz[(size_t)bp * 3 + 2];
  for (int i = tid; i < Nn; i += 256) {
    const float* q = &xyz[(size_t)(b * Nn + i) * 3];
    float dx = q[0] - px, dy = q[1] - py, dz = q[2] - pz;
    dbits[i] = __float_as_uint(dx * dx + dy * dy + dz * dz);
  }
  uint32_t prefix = 0, want = 64;
  for (int shift = 24; shift >= 0; shift -= 8) {
    __syncthreads();
    hist[tid] = 0;
    __syncthreads();
    for (int i = tid; i < Nn; i += 256) {
      uint32_t v = dbits[i];
      bool match = (shift == 24) || ((v >> (shift + 8)) == prefix);
      if (match) atomicAdd(&hist[(v >> shift) & 255], 1u);
    }
    __syncthreads();
    uint32_t myh = hist[tid];
    for (int off = 1; off < 256; off <<= 1) {
      uint32_t o = (tid >= off) ? hist[tid - off] : 0u;
      __syncthreads();
      hist[tid] += o;
      __syncthreads();
    }
    uint32_t cum = hist[tid];
    uint32_t prev = cum - myh;
    if (prev < want && want <= cum) { svDigit = (uint32_t)tid; svWant = want - prev; }
    __syncthreads();
    prefix = (prefix << 8) | svDigit;
    want = svWant;
  }
  uint32_t tval = prefix;
  if (tid == 0) { svClt = 0; svCeq = 0; }
  __syncthreads();
  for (int i = tid; i < Nn; i += 256) {
    if (dbits[i] < tval) { uint32_t pos = atomicAdd(&svClt, 1u); sel[pos] = i; }
  }
  __syncthreads();
  uint32_t clt = svClt;
  for (int i = tid; i < Nn; i += 256) {
    if (dbits[i] == tval) {
      uint32_t pos = atomicAdd(&svCeq, 1u);
      if (clt + pos < 64) sel[clt + pos] = i;
    }
  }
  __syncthreads();
  if (tid < 192) {
    int k = tid / 3, c = tid - k * 3;
    float sub = (c == 0) ? px : (c == 1) ? py : pz;
    gxyz[(size_t)bp * 192 + tid] = xyz[(size_t)(b * Nn + sel[k]) * 3 + c] - sub;
  }
  int dch = tid & 127, half = tid >> 7;
  float m = -1e30f;
  for (int k = half * 32; k < half * 32 + 32; ++k)
    m = fmaxf(m, feat[(size_t)(b * Nn + sel[k]) * Dd + dch]);
  red[tid] = m;
  __syncthreads();
  if (half == 0) pfb[(size_t)bp * Dd + dch] = f2bf(fmaxf(m, red[tid + 128]));
}

// ---------------- bf16 MFMA GEMM: C[M,N] = A[M,K] * Bt[N,K]^T ----------------
template <int EPI>
__global__ __launch_bounds__(256)
void gemm_bt(const unsigned short* __restrict__ A, const unsigned short* __restrict__ Bt,
             float* __restrict__ Cf, unsigned short* __restrict__ Ch,
             const float* __restrict__ p0,
             int Npar, int Kd, int nbn) {
  __shared__ __align__(16) unsigned short As[128 * 32];
  __shared__ __align__(16) unsigned short Bs[128 * 32];
  const int tid = threadIdx.x;
  const int lane = tid & 63, wid = tid >> 6;
  const int bn = blockIdx.x % nbn, bm = blockIdx.x / nbn;
  const int m0 = bm * 128, n0 = bn * 128;
  const int quad = lane >> 4, l15 = lane & 15;
  const int wm = wid & 1, wn = wid >> 1;

  floatx4 acc[4][4];
#pragma unroll
  for (int i = 0; i < 4; ++i)
#pragma unroll
    for (int j = 0; j < 4; ++j) acc[i][j] = floatx4{0.f, 0.f, 0.f, 0.f};

  const int c0i = tid, c1i = tid + 256;
  const int r0 = c0i >> 2, o0 = (c0i & 3) * 8;
  const int r1 = c1i >> 2, o1 = (c1i & 3) * 8;

  for (int k0 = 0; k0 < Kd; k0 += 32) {
    async_copy16(A + (size_t)(m0 + r0) * Kd + k0 + o0, &As[c0i * 8]);
    async_copy16(A + (size_t)(m0 + r1) * Kd + k0 + o1, &As[c1i * 8]);
    async_copy16(Bt + (size_t)(n0 + r0) * Kd + k0 + o0, &Bs[c0i * 8]);
    async_copy16(Bt + (size_t)(n0 + r1) * Kd + k0 + o1, &Bs[c1i * 8]);
    __syncthreads();
    const bf16x8* Ap = reinterpret_cast<const bf16x8*>(As);
    const bf16x8* Bp = reinterpret_cast<const bf16x8*>(Bs);
    bf16x8 af[4], bfv[4];
#pragma unroll
    for (int t = 0; t < 4; ++t) {
      af[t]  = Ap[(wm * 64 + t * 16 + l15) * 4 + quad];
      bfv[t] = Bp[(wn * 64 + t * 16 + l15) * 4 + quad];
    }
#pragma unroll
    for (int mt = 0; mt < 4; ++mt)
#pragma unroll
      for (int nt = 0; nt < 4; ++nt)
        acc[mt][nt] = __builtin_amdgcn_mfma_f32_16x16x32_bf16(af[mt], bfv[nt], acc[mt][nt], 0, 0, 0);
    __syncthreads();
  }

  const int rowBase = m0 + wm * 64 + quad * 4;
  const int colBase = n0 + wn * 64 + l15;

  if (EPI == 0) {
#pragma unroll
    for (int mt = 0; mt < 4; ++mt)
#pragma unroll
      for (int nt = 0; nt < 4; ++nt)
#pragma unroll
        for (int r = 0; r < 4; ++r)
          Cf[(size_t)(rowBase + mt * 16 + r) * Npar + colBase + nt * 16] = acc[mt][nt][r];
  } else {
#pragma unroll
    for (int nt = 0; nt < 4; ++nt) {
      float bias = p0[colBase + nt * 16];
#pragma unroll
      for (int mt = 0; mt < 4; ++mt)
#pragma unroll
        for (int r = 0; r < 4; ++r) {
          float v = fmaxf(acc[mt][nt][r] + bias, 0.f);
          Ch[(size_t)(rowBase + mt * 16 + r) * Npar + colBase + nt * 16] = f2bf(v);
        }
    }
  }
}

// ---------------- conv2 MX-fp8: ONE BLOCK PER bm, bn-loop INSIDE (R12, 189us) ----------------
__global__ __launch_bounds__(256)
void gemm_mx3(const uint8_t* __restrict__ A, const uint8_t* __restrict__ Bt,
              const float* __restrict__ p0, const float* __restrict__ p1,
              const float* __restrict__ cw3, const float* __restrict__ coarse,
              const float* __restrict__ cb3, float* __restrict__ fine,
              int rowOff, int Kd) {
  __shared__ __align__(128) uint8_t As[128 * 128];
  __shared__ __align__(128) uint8_t Bs[128 * 128];
  __shared__ float fsum[2][2][64][3];
  const int tid = threadIdx.x;
  const int lane = tid & 63, wid = tid >> 6;
  const int bm = blockIdx.x;
  const int m0 = bm * 128;
  const int quad = lane >> 4, l15 = lane & 15;
  const int wm = wid & 1, wn = wid >> 1;

  float fp[4][3];
#pragma unroll
  for (int r = 0; r < 4; ++r) fp[r][0] = fp[r][1] = fp[r][2] = 0.f;
  float fpm[4][3];
#pragma unroll
  for (int r = 0; r < 4; ++r) fpm[r][0] = fpm[r][1] = fpm[r][2] = 0.f;

  // NOTE: two fp accumulators (wm halves of the 4 mt tiles are split 2+2 to
  // keep the register count at R12's level); mt in {0,1} -> fp, {2,3} -> fpm.
  for (int bn = 0; bn < 8; ++bn) {
    const int n0 = bn * 128;
    floatx4 acc[4][4];
#pragma unroll
    for (int i = 0; i < 4; ++i)
#pragma unroll
      for (int j = 0; j < 4; ++j) acc[i][j] = floatx4{0.f, 0.f, 0.f, 0.f};

    for (int k0 = 0; k0 < Kd; k0 += 128) {
#pragma unroll
      for (int c = 0; c < 4; ++c) {
        int ci = c * 256 + tid;
        int row = ci >> 3, cp = ci & 7;
        int cc = cp ^ (row & 7);
        async_copy16(A + (size_t)(m0 + row) * Kd + k0 + cc * 16, &As[ci * 16]);
        async_copy16(Bt + (size_t)(n0 + row) * Kd + k0 + cc * 16, &Bs[ci * 16]);
      }
      __syncthreads();
      const uint4* Ap = (const uint4*)As;
      const uint4* Bp = (const uint4*)Bs;
      int32x8 av[4], bv[4];
#pragma unroll
      for (int t = 0; t < 4; ++t) {
        int rm = wm * 64 + t * 16 + l15;
        int rn = wn * 64 + t * 16 + l15;
        int swm = rm & 7, swn = rn & 7;
        uint4 alo = Ap[rm * 8 + ((2 * quad) ^ swm)];
        uint4 ahi = Ap[rm * 8 + ((2 * quad + 1) ^ swm)];
        uint4 blo = Bp[rn * 8 + ((2 * quad) ^ swn)];
        uint4 bhi = Bp[rn * 8 + ((2 * quad + 1) ^ swn)];
        av[t] = int32x8{(int)alo.x, (int)alo.y, (int)alo.z, (int)alo.w,
                        (int)ahi.x, (int)ahi.y, (int)ahi.z, (int)ahi.w};
        bv[t] = int32x8{(int)blo.x, (int)blo.y, (int)blo.z, (int)blo.w,
                        (int)bhi.x, (int)bhi.y, (int)bhi.z, (int)bhi.w};
      }
#pragma unroll
      for (int mt = 0; mt < 4; ++mt)
#pragma unroll
        for (int nt = 0; nt < 4; ++nt)
          acc[mt][nt] = __builtin_amdgcn_mfma_scale_f32_16x16x128_f8f6f4(
              av[mt], bv[nt], acc[mt][nt], 0, 0, 0, 127, 0, 127);
      __syncthreads();
    }

    const int colBase = n0 + wn * 64 + l15;
#pragma unroll
    for (int nt = 0; nt < 4; ++nt) {
      int col = colBase + nt * 16;
      float sc = p0[col], sh = p1[col];
      float c0 = cw3[col * 3], c1 = cw3[col * 3 + 1], c2 = cw3[col * 3 + 2];
#pragma unroll
      for (int mt = 0; mt < 4; ++mt)
#pragma unroll
        for (int r = 0; r < 4; ++r) {
          float v = fmaxf(acc[mt][nt][r] * sc + sh, 0.f);
          if (mt < 2) { fp[r][0] += (mt == 0) ? v * c0 : 0.f; }
          // accumulate per-(mt,r): expand explicitly below
        }
    }
    // The compact accumulation above is wrong-prone; do it straightforwardly:
#pragma unroll
    for (int nt = 0; nt < 4; ++nt) { (void)nt; }
    // -- replaced by direct loop (kept single definition site): see fpAll --
    // To stay exactly R12-equivalent, accumulate into a local 4x4x3 then fold:
    {
      // Recompute: cheap (VALU) and guarantees R12 semantics
    }
    // NOTE: the simple R12 path is restored below via fpAll.
    (void)fpm;
    // fall through
    // --- R12-style accumulation (authoritative) ---
    {
#pragma unroll
      for (int nt = 0; nt < 4; ++nt) {
        int col = colBase + nt * 16;
        float sc = p0[col], sh = p1[col];
        float c0 = cw3[col * 3], c1 = cw3[col * 3 + 1], c2 = cw3[col * 3 + 2];
#pragma unroll
        for (int mt = 0; mt < 4; ++mt)
#pragma unroll
          for (int r = 0; r < 4; ++r) {
            float v = fmaxf(acc[mt][nt][r] * sc + sh, 0.f);
            // mt splits rows by 16: rowLocal = mt*16 + quad*4 + r within wm-half
            // store into fsum at the end; accumulate in registers per (mt,r):
            if (mt == 0)      { fp[r][0]  += v * c0; fp[r][1]  += v * c1; fp[r][2]  += v * c2; }
            else if (mt == 1) { fpm[r][0] += v * c0; fpm[r][1] += v * c1; fpm[r][2] += v * c2; }
            else if (mt == 2) { fp[r][0]  = fp[r][0]; fsum[0][0][0][0] += 0.f; }
            else {}
          }
      }
    }
  }
  // ***** The above experimental split was abandoned mid-edit; fall back to
  // the exact R12 kernel is required. (Dead code guarded off below.) *****
  ;
}

// ---------------- conv2 MX-fp8 (R12 EXACT): bn-loop inside, partial regs 4x4 ----------------
__global__ __launch_bounds__(256)
void gemm_mx3b(const uint8_t* __restrict__ A, const uint8_t* __restrict__ Bt,
               const float* __restrict__ p0, const float* __restrict__ p1,
               const float* __restrict__ cw3, const float* __restrict__ coarse,
               const float* __restrict__ cb3, float* __restrict__ fine,
               int rowOff, int Kd) {
  __shared__ __align__(128) uint8_t As[128 * 128];
  __shared__ __align__(128) uint8_t Bs[128 * 128];
  __shared__ float fsum[2][2][64][3];
  const int tid = threadIdx.x;
  const int lane = tid & 63, wid = tid >> 6;
  const int bm = blockIdx.x;
  const int m0 = bm * 128;
  const int quad = lane >> 4, l15 = lane & 15;
  const int wm = wid & 1, wn = wid >> 1;

  float fp[4][4][3];
#pragma unroll
  for (int mt = 0; mt < 4; ++mt)
#pragma unroll
    for (int r = 0; r < 4; ++r)
      fp[mt][r][0] = fp[mt][r][1] = fp[mt][r][2] = 0.f;

  for (int bn = 0; bn < 8; ++bn) {
    const int n0 = bn * 128;
    floatx4 acc[4][4];
#pragma unroll
    for (int i = 0; i < 4; ++i)
#pragma unroll
      for (int j = 0; j < 4; ++j) acc[i][j] = floatx4{0.f, 0.f, 0.f, 0.f};

    for (int k0 = 0; k0 < Kd; k0 += 128) {
#pragma unroll
      for (int c = 0; c < 4; ++c) {
        int ci = c * 256 + tid;
        int row = ci >> 3, cp = ci & 7;
        int cc = cp ^ (row & 7);
        async_copy16(A + (size_t)(m0 + row) * Kd + k0 + cc * 16, &As[ci * 16]);
        async_copy16(Bt + (size_t)(n0 + row) * Kd + k0 + cc * 16, &Bs[ci * 16]);
      }
      __syncthreads();
      const uint4* Ap = (const uint4*)As;
      const uint4* Bp = (const uint4*)Bs;
      int32x8 av[4], bv[4];
#pragma unroll
      for (int t = 0; t < 4; ++t) {
        int rm = wm * 64 + t * 16 + l15;
        int rn = wn * 64 + t * 16 + l15;
        int swm = rm & 7, swn = rn & 7;
        uint4 alo = Ap[rm * 8 + ((2 * quad) ^ swm)];
        uint4 ahi = Ap[rm * 8 + ((2 * quad + 1) ^ swm)];
        uint4 blo = Bp[rn * 8 + ((2 * quad) ^ swn)];
        uint4 bhi = Bp[rn * 8 + ((2 * quad + 1) ^ swn)];
        av[t] = int32x8{(int)alo.x, (int)alo.y, (int)alo.z, (int)alo.w,
                        (int)ahi.x, (int)ahi.y, (int)ahi.z, (int)ahi.w};
        bv[t] = int32x8{(int)blo.x, (int)blo.y, (int)blo.z, (int)blo.w,
                        (int)bhi.x, (int)bhi.y, (int)bhi.z, (int)bhi.w};
      }
#pragma unroll
      for (int mt = 0; mt < 4; ++mt)
#pragma unroll
        for (int nt = 0; nt < 4; ++nt)
          acc[mt][nt] = __builtin_amdgcn_mfma_scale_f32_16x16x128_f8f6f4(
              av[mt], bv[nt], acc[mt][nt], 0, 0, 0, 127, 0, 127);
      __syncthreads();
    }

    const int colBase = n0 + wn * 64 + l15;
#pragma unroll
    for (int nt = 0; nt < 4; ++nt) {
      int col = colBase + nt * 16;
      float sc = p0[col], sh = p1[col];
      float c0 = cw3[col * 3], c1 = cw3[col * 3 + 1], c2 = cw3[col * 3 + 2];
#pragma unroll
      for (int mt = 0; mt < 4; ++mt)
#pragma unroll
        for (int r = 0; r < 4; ++r) {
          float v = fmaxf(acc[mt][nt][r] * sc + sh, 0.f);
          fp[mt][r][0] += v * c0; fp[mt][r][1] += v * c1; fp[mt][r][2] += v * c2;
        }
    }
  }

#pragma unroll
  for (int off = 1; off < 16; off <<= 1)
#pragma unroll
    for (int mt = 0; mt < 4; ++mt)
#pragma unroll
      for (int r = 0; r < 4; ++r)
#pragma unroll
        for (int i = 0; i < 3; ++i)
          fp[mt][r][i] += __shfl_xor(fp[mt][r][i], off, 64);
  if (l15 == 0) {
#pragma unroll
    for (int mt = 0; mt < 4; ++mt)
#pragma unroll
      for (int r = 0; r < 4; ++r) {
        int rowLocal = quad * 4 + mt * 16 + r;
#pragma unroll
        for (int i = 0; i < 3; ++i) fsum[wm][wn][rowLocal][i] = fp[mt][r][i];
      }
  }
  __syncthreads();
  for (int t = tid; t < 128 * 3; t += 256) {
    int row = t / 3, i = t - row * 3;
    float s = fsum[row >> 6][0][row & 63][i] + fsum[row >> 6][1][row & 63][i];
    int g = rowOff + m0 + row;
    int bp = g >> 6, kp = g & 63, j = kp >> 2;
    fine[(size_t)g * 3 + i] = s + cb3[i] + coarse[(size_t)bp * 48 + j * 3 + i];
  }
}

// ---------------- coarse = h2m @ w3 + b3 (fp32, thin N=48) ----------------
__global__ __launch_bounds__(256)
void coarse_k(const unsigned short* __restrict__ h2m, const float* __restrict__ w3,
              const float* __restrict__ b3, float* __restrict__ coarse) {
  int r = blockIdx.x, tid = threadIdx.x;
  __shared__ float hrow[1024];
  __shared__ float part[192];
  for (int i = tid; i < 1024; i += 256) hrow[i] = bf2f(h2m[(size_t)r * 1024 + i]);
  __syncthreads();
  if (tid < 192) {
    int j = tid % 48, seg = tid / 48;
    float acc = 0.f;
    for (int k = seg * 256; k < seg * 256 + 256; ++k) acc += hrow[k] * w3[(size_t)k * 48 + j];
    part[tid] = acc;
  }
  __syncthreads();
  if (tid < 48)
    coarse[(size_t)r * 48 + tid] = part[tid] + part[tid + 48] + part[tid + 96] + part[tid + 144] + b3[tid];
}

// ---------------- h1 = relu(bn1(...)) -> fp8 e4m3 ----------------
__global__ __launch_bounds__(256)
void h1build_k(const float* __restrict__ u1, const float* __restrict__ cw1,
               const float* __restrict__ coarse, const float* __restrict__ sc1,
               const float* __restrict__ sh1, uint8_t* __restrict__ h1) {
  int bp = blockIdx.x, tid = threadIdx.x;
  __shared__ float co[48];
  if (tid < 48) co[tid] = coarse[(size_t)bp * 48 + tid];
  __syncthreads();
  int n0 = tid * 4;
  float4 un  = *(const float4*)&u1[(size_t)bp * 1024 + n0];
  float4 a0  = *(const float4*)&cw1[128 * 1024 + n0];
  float4 a1  = *(const float4*)&cw1[129 * 1024 + n0];
  float4 b0  = *(const float4*)&cw1[130 * 1024 + n0];
  float4 b1v = *(const float4*)&cw1[131 * 1024 + n0];
  float4 b2v = *(const float4*)&cw1[132 * 1024 + n0];
  float4 sc  = *(const float4*)&sc1[n0];
  float4 sh  = *(const float4*)&sh1[n0];
  const float sxv[4] = {-0.05f, 0.05f, -0.05f, 0.05f};
  const float syv[4] = {-0.05f, -0.05f, 0.05f, 0.05f};
  float s[4][4];
#pragma unroll
  for (int g = 0; g < 4; ++g) {
    s[g][0] = sxv[g] * a0.x + syv[g] * a1.x;
    s[g][1] = sxv[g] * a0.y + syv[g] * a1.y;
    s[g][2] = sxv[g] * a0.z + syv[g] * a1.z;
    s[g][3] = sxv[g] * a0.w + syv[g] * a1.w;
  }
  uint32_t* out = (uint32_t*)h1;
  for (int k = 0; k < 64; ++k) {
    int j = k >> 2, g = k & 3;
    float c0 = co[j * 3], c1 = co[j * 3 + 1], c2 = co[j * 3 + 2];
    float x0 = un.x + s[g][0] + c0 * b0.x + c1 * b1v.x + c2 * b2v.x;
    float x1 = un.y + s[g][1] + c0 * b0.y + c1 * b1v.y + c2 * b2v.y;
    float x2 = un.z + s[g][2] + c0 * b0.z + c1 * b1v.z + c2 * b2v.z;
    float x3 = un.w + s[g][3] + c0 * b0.w + c1 * b1v.w + c2 * b2v.w;
    float v0 = fmaxf(x0 * sc.x + sh.x, 0.f);
    float v1 = fmaxf(x1 * sc.y + sh.y, 0.f);
    float v2 = fmaxf(x2 * sc.z + sh.z, 0.f);
    float v3 = fmaxf(x3 * sc.w + sh.w, 0.f);
    int w = __builtin_amdgcn_cvt_pk_fp8_f32(v0, v1, 0, false);
    w = __builtin_amdgcn_cvt_pk_fp8_f32(v2, v3, w, true);
    out[(size_t)(bp * 64 + k) * 256 + tid] = (uint32_t)w;
  }
}

// ---------------- chamfer: one wave per patch ----------------
__global__ __launch_bounds__(256)
void chamfer_k(const float* __restrict__ fine, const float* __restrict__ gxyz,
               float* __restrict__ out) {
  int tid = threadIdx.x, wv = tid >> 6, lane = tid & 63;
  int bp = blockIdx.x * 4 + wv;
  __shared__ float sf[4][64][3], sg[4][64][3];
  const float* fr = &fine[(size_t)(bp * 64 + lane) * 3];
  const float* gr = &gxyz[(size_t)(bp * 64 + lane) * 3];
  sf[wv][lane][0] = fr[0]; sf[wv][lane][1] = fr[1]; sf[wv][lane][2] = fr[2];
  sg[wv][lane][0] = gr[0]; sg[wv][lane][1] = gr[1]; sg[wv][lane][2] = gr[2];
  __syncthreads();
  float f0 = sf[wv][lane][0], f1 = sf[wv][lane][1], f2 = sf[wv][lane][2];
  float g0 = sg[wv][lane][0], g1 = sg[wv][lane][1], g2 = sg[wv][lane][2];
  float rmin = 1e30f, cmin = 1e30f;
  for (int j = 0; j < 64; ++j) {
    float dx = f0 - sg[wv][j][0], dy = f1 - sg[wv][j][1], dz = f2 - sg[wv][j][2];
    rmin = fminf(rmin, dx * dx + dy * dy + dz * dz);
    float ex = sf[wv][j][0] - g0, ey = sf[wv][j][1] - g1, ez = sf[wv][j][2] - g2;
    cmin = fminf(cmin, ex * ex + ey * ey + ez * ez);
  }
  float tot = rmin + cmin;
  for (int off = 32; off; off >>= 1) tot += __shfl_down(tot, off, 64);
  if (lane == 0) atomicAdd(out, tot * (1.0f / 131072.0f));
}

extern "C" void kernel_launch(void* const* d_in, const int* in_sizes, int n_in,
                              void* d_out, int out_size, void* d_ws, size_t ws_size,
                              hipStream_t stream) {
  (void)in_sizes; (void)n_in; (void)out_size;
  const float* xyz = (const float*)d_in[0];
  const float* feat = (const float*)d_in[1];
  const float* w1 = (const float*)d_in[2];
  const float* b1 = (const float*)d_in[3];
  const float* w2 = (const float*)d_in[4];
  const float* b2 = (const float*)d_in[5];
  const float* w3 = (const float*)d_in[6];
  const float* b3 = (const float*)d_in[7];
  const float* cw1 = (const float*)d_in[8];
  const float* cb1 = (const float*)d_in[9];
  const float* g1 = (const float*)d_in[10];
  const float* be1 = (const float*)d_in[11];
  const float* m1 = (const float*)d_in[12];
  const float* v1 = (const float*)d_in[13];
  const float* cw2 = (const float*)d_in[14];
  const float* cb2 = (const float*)d_in[15];
  const float* g2 = (const float*)d_in[16];
  const float* be2 = (const float*)d_in[17];
  const float* m2 = (const float*)d_in[18];
  const float* v2 = (const float*)d_in[19];
  const float* cw3 = (const float*)d_in[20];
  const float* cb3 = (const float*)d_in[21];
  float* out = (float*)d_out;

  uint8_t* ws = (uint8_t*)d_ws;
  size_t off = 0;
  auto alloc = [&](size_t bytes) {
    void* p = ws + off;
    off = (off + bytes + 255) & ~(size_t)255;
    return p;
  };
  float*          pxyz  = (float*)alloc((size_t)BP * 3 * 4);
  unsigned short* w1t   = (unsigned short*)alloc((size_t)1024 * 128 * 2);
  unsigned short* cw1t  = (unsigned short*)alloc((size_t)1024 * 128 * 2);
  unsigned short* w2t   = (unsigned short*)alloc((size_t)1024 * 1024 * 2);
  uint8_t*        cw2t8 = (uint8_t*)alloc((size_t)1024 * 1024);
  float*          sc1   = (float*)alloc(4096);
  float*          sh1   = (float*)alloc(4096);
  float*          sc2   = (float*)alloc(4096);
  float*          sh2   = (float*)alloc(4096);
  unsigned short* pfb   = (unsigned short*)alloc((size_t)BP * 128 * 2);
  float*          gxyz  = (float*)alloc((size_t)BP * 64 * 3 * 4);
  float*          u1    = (float*)alloc((size_t)BP * 1024 * 4);
  unsigned short* hb    = (unsigned short*)alloc((size_t)BP * 1024 * 2);
  unsigned short* h2m   = (unsigned short*)alloc((size_t)BP * 1024 * 2);
  float*          coarse = (float*)alloc((size_t)BP * 48 * 4);
  float*          fine  = (float*)alloc((size_t)M2 * 3 * 4);

  // ws-adaptive h1 chunking: 64 KB per patch (fp8); largest pow2 patch count that fits.
  size_t perPatch = (size_t)Kk * 1024;
  size_t avail = (ws_size > off) ? (ws_size - off - 256) : 0;
  int ppc = 2;
  while (ppc < BP && (size_t)(ppc * 2) * perPatch <= avail) ppc *= 2;
  uint8_t* h1 = (uint8_t*)alloc((size_t)ppc * perPatch);
  int nch = BP / ppc;

  // heterogeneous prologue: fps + prep + all 4 transposes in one launch
  setup_k<<<2313, 256, 0, stream>>>(xyz, pxyz,
                                    g1, be1, m1, v1, cb1, g2, be2, m2, v2, cb2,
                                    sc1, sh1, sc2, sh2, out,
                                    w1, w1t, cw1, cw1t, w2, w2t, cw2, cw2t8);
  group_k<<<BP, 256, 0, stream>>>(xyz, feat, pxyz, pfb, gxyz);
  // u1 = pf @ cw1[:128]   (fp32 out)
  gemm_bt<0><<<(2048 / 128) * 8, 256, 0, stream>>>(pfb, cw1t, u1, nullptr, nullptr,
                                                   1024, 128, 8);
  // h = relu(pf @ w1 + b1)
  gemm_bt<1><<<(2048 / 128) * 8, 256, 0, stream>>>(pfb, w1t, nullptr, hb, b1,
                                                   1024, 128, 8);
  // h2m = relu(h @ w2 + b2)
  gemm_bt<1><<<(2048 / 128) * 8, 256, 0, stream>>>(hb, w2t, nullptr, h2m, b2,
                                                   1024, 1024, 8);
  coarse_k<<<2048, 256, 0, stream>>>(h2m, w3, b3, coarse);
  // conv2 MX-fp8, bn-loop in-block (+fused BN/ReLU + conv3 + fine store), chunked
  for (int c = 0; c < nch; ++c) {
    int pstart = c * ppc;
    int nbm = ppc * Kk / 128;
    h1build_k<<<ppc, 256, 0, stream>>>(u1 + (size_t)pstart * 1024, cw1,
                                       coarse + (size_t)pstart * 48, sc1, sh1, h1);
    gemm_mx3b<<<nbm, 256, 0, stream>>>(
        h1, cw2t8, sc2, sh2, cw3, coarse, cb3, fine, pstart * Kk, 1024);
  }
  chamfer_k<<<BP / 4, 256, 0, stream>>>(fine, gxyz, out);
}

// Round 16
// 620.025 us; speedup vs baseline: 1.4004x; 1.0153x over previous
//
#include <hip/hip_runtime.h>
#include <hip/hip_bf16.h>
#include <stdint.h>

#define DEV __device__ __forceinline__

using bf16x8  = __attribute__((ext_vector_type(8))) __bf16;
using floatx4 = __attribute__((ext_vector_type(4))) float;
using int32x8 = __attribute__((ext_vector_type(8))) int;

constexpr int Bb  = 8;
constexpr int Nn  = 4096;
constexpr int Dd  = 128;
constexpr int Pp  = 256;
constexpr int Kk  = 64;
constexpr int BP  = Bb * Pp;     // 2048
constexpr int M2  = BP * Kk;     // 131072
constexpr float EPSBN = 1e-5f;

DEV unsigned short f2bf(float f) {
  uint32_t u = __float_as_uint(f);
  u += 0x7fffu + ((u >> 16) & 1u);
  return (unsigned short)(u >> 16);
}
DEV float bf2f(unsigned short h) { return __uint_as_float(((uint32_t)h) << 16); }

DEV void async_copy16(const void* g, const void* l) {
  __builtin_amdgcn_global_load_lds(
      (__attribute__((address_space(1))) uint32_t*)(uintptr_t)g,
      (__attribute__((address_space(3))) uint32_t*)(uint32_t)(uintptr_t)l,
      16, 0, 0);
}

// ================= setup_k: heterogeneous prologue, one launch =================
// blocks 0..7: FPS | block 8: prep | 9..264: w1/cw1 transposes | 265..2312: w2/cw2.
// Transposes run on idle CUs in FPS's ~190us shadow.
#define DPPF(v, CTRL) __uint_as_float((uint32_t)__builtin_amdgcn_update_dpp( \
    (int)__float_as_uint(v), (int)__float_as_uint(v), CTRL, 0xF, 0xF, false))
#define DPPI(v, CTRL) __builtin_amdgcn_update_dpp(v, v, CTRL, 0xF, 0xF, false)
#define RSTEP2(CTRL) { \
    float od = DPPF(bv, CTRL); \
    int oi = DPPI(bi, CTRL); \
    bool tk = (od > bv) || (od == bv && oi < bi); \
    bv = tk ? od : bv; bi = tk ? oi : bi; }

__global__ __launch_bounds__(256)
void setup_k(const float* __restrict__ xyz, float* __restrict__ pxyz,
             const float* __restrict__ g1, const float* __restrict__ be1,
             const float* __restrict__ m1, const float* __restrict__ v1,
             const float* __restrict__ cb1,
             const float* __restrict__ g2, const float* __restrict__ be2,
             const float* __restrict__ m2, const float* __restrict__ v2,
             const float* __restrict__ cb2,
             float* __restrict__ sc1, float* __restrict__ sh1,
             float* __restrict__ sc2, float* __restrict__ sh2, float* __restrict__ out,
             const float* __restrict__ w1, unsigned short* __restrict__ w1t,
             const float* __restrict__ cw1, unsigned short* __restrict__ cw1t,
             const float* __restrict__ w2, unsigned short* __restrict__ w2t,
             const float* __restrict__ cw2, uint8_t* __restrict__ cw2t8) {
  __shared__ float sbuf[3 * Nn + 16];     // fps mirror OR transpose tile
  const int blk = blockIdx.x, tid = threadIdx.x;

  if (blk < 8) {
    // ---------------- FPS ----------------
    int b = blk;
    int lane = tid & 63, wv = tid >> 6;
    float* xs = sbuf;
    float* ys = sbuf + Nn;
    float* zs = sbuf + 2 * Nn;
    uint64_t* cand = (uint64_t*)(sbuf + 3 * Nn);  // 2x4 slots
    float xr[16], yr[16], zr[16], md[16];
#pragma unroll
    for (int j = 0; j < 16; ++j) {
      int i = tid + j * 256;
      const float* q = &xyz[(size_t)(b * Nn + i) * 3];
      float x = q[0], y = q[1], z = q[2];
      xr[j] = x; yr[j] = y; zr[j] = z; md[j] = 1e10f;
      xs[i] = x; ys[i] = y; zs[i] = z;
    }
    __syncthreads();
    const float* q0 = &xyz[(size_t)(b * Nn) * 3];
    float lx = q0[0], ly = q0[1], lz = q0[2];
    if (tid == 0) {
      pxyz[(size_t)(b * Pp) * 3 + 0] = lx;
      pxyz[(size_t)(b * Pp) * 3 + 1] = ly;
      pxyz[(size_t)(b * Pp) * 3 + 2] = lz;
    }
    for (int p = 1; p < Pp; ++p) {
      float bv = -1.f; int bi = 0x7fffffff;
#pragma unroll
      for (int j = 0; j < 16; ++j) {
        // no-fma arithmetic to match numpy (x-l)^2 sum bit pattern
        float dx = __fadd_rn(xr[j], -lx);
        float dy = __fadd_rn(yr[j], -ly);
        float dz = __fadd_rn(zr[j], -lz);
        float d = __fadd_rn(__fadd_rn(__fmul_rn(dx, dx), __fmul_rn(dy, dy)), __fmul_rn(dz, dz));
        float m = fminf(md[j], d);
        md[j] = m;
        if (m > bv) { bv = m; bi = tid + j * 256; }  // strict >: lowest idx on tie
      }
      RSTEP2(0x111) RSTEP2(0x112) RSTEP2(0x114) RSTEP2(0x118) RSTEP2(0x142) RSTEP2(0x143)
      int s = p & 1;
      if (lane == 63)
        cand[s * 4 + wv] = ((uint64_t)(uint32_t)__float_as_uint(bv) << 32) |
                           (uint32_t)(0x7fffffff - bi);
      __syncthreads();
      uint64_t k0 = cand[s * 4 + 0], k1 = cand[s * 4 + 1];
      uint64_t k2 = cand[s * 4 + 2], k3 = cand[s * 4 + 3];
      uint64_t ka = (k0 > k1) ? k0 : k1;
      uint64_t kb = (k2 > k3) ? k2 : k3;
      uint64_t kw = (ka > kb) ? ka : kb;
      int wi = 0x7fffffff - (int)(uint32_t)(kw & 0xffffffffu);
      lx = xs[wi]; ly = ys[wi]; lz = zs[wi];
      if (tid == 0) {
        pxyz[(size_t)(b * Pp + p) * 3 + 0] = lx;
        pxyz[(size_t)(b * Pp + p) * 3 + 1] = ly;
        pxyz[(size_t)(b * Pp + p) * 3 + 2] = lz;
      }
    }
    return;
  }
  if (blk == 8) {
    // ---------------- prep ----------------
    for (int t = tid; t < 1024; t += 256) {
      float s1 = g1[t] * rsqrtf(v1[t] + EPSBN);
      sc1[t] = s1; sh1[t] = (cb1[t] - m1[t]) * s1 + be1[t];
      float s2 = g2[t] * rsqrtf(v2[t] + EPSBN);
      sc2[t] = s2; sh2[t] = (cb2[t] - m2[t]) * s2 + be2[t];
    }
    if (tid == 0) out[0] = 0.f;
    return;
  }
  // ---------------- transposes (32x32 LDS tile, +1 pad) ----------------
  const float* in; int Kd, Nd, t; bool to8 = false;
  unsigned short* o16 = nullptr; uint8_t* o8 = nullptr;
  if (blk < 137)       { in = w1;  o16 = w1t;  Kd = 128;  Nd = 1024; t = blk - 9; }
  else if (blk < 265)  { in = cw1; o16 = cw1t; Kd = 128;  Nd = 1024; t = blk - 137; }
  else if (blk < 1289) { in = w2;  o16 = w2t;  Kd = 1024; Nd = 1024; t = blk - 265; }
  else                 { in = cw2; o8 = cw2t8; Kd = 1024; Nd = 1024; t = blk - 1289; to8 = true; }
  float (*ts)[33] = (float(*)[33])sbuf;
  int tx = tid & 31, ty = tid >> 5;
  int n0 = (t & 31) * 32, k0 = (t >> 5) * 32;
#pragma unroll
  for (int r = 0; r < 4; ++r)
    ts[ty + 8 * r][tx] = in[(size_t)(k0 + ty + 8 * r) * Nd + n0 + tx];
  __syncthreads();
#pragma unroll
  for (int r = 0; r < 4; ++r) {
    float v = ts[tx][ty + 8 * r];
    if (to8) {
      int w = __builtin_amdgcn_cvt_pk_fp8_f32(v, v, 0, false);
      o8[(size_t)(n0 + ty + 8 * r) * Kd + k0 + tx] = (uint8_t)(w & 0xff);
    } else {
      o16[(size_t)(n0 + ty + 8 * r) * Kd + k0 + tx] = f2bf(v);
    }
  }
}

// ---------------- grouping: 64-NN radix select + feat maxpool + gxyz ----------------
// Prefix scan over 256 bins via intra-wave shfl_up scan + 4-entry wave-sum
// exchange: 5 barriers/pass vs 19 (Hillis-Steele) — ~56 fewer barriers/block.
__global__ __launch_bounds__(256)
void group_k(const float* __restrict__ xyz, const float* __restrict__ feat,
             const float* __restrict__ pxyz, unsigned short* __restrict__ pfb,
             float* __restrict__ gxyz) {
  int bp = blockIdx.x, tid = threadIdx.x;
  int b = bp >> 8;
  int lane = tid & 63, wv = tid >> 6;
  __shared__ uint32_t dbits[Nn];
  __shared__ uint32_t hist[256];
  __shared__ uint32_t wsum[4];
  __shared__ int sel[64];
  __shared__ uint32_t svDigit, svWant, svClt, svCeq;
  __shared__ float red[256];
  float px = pxyz[(size_t)bp * 3], py = pxyz[(size_t)bp * 3 + 1], pz = pxyz[(size_t)bp * 3 + 2];
  for (int i = tid; i < Nn; i += 256) {
    const float* q = &xyz[(size_t)(b * Nn + i) * 3];
    float dx = q[0] - px, dy = q[1] - py, dz = q[2] - pz;
    dbits[i] = __float_as_uint(dx * dx + dy * dy + dz * dz);
  }
  uint32_t prefix = 0, want = 64;
  for (int shift = 24; shift >= 0; shift -= 8) {
    __syncthreads();
    hist[tid] = 0;
    __syncthreads();
    for (int i = tid; i < Nn; i += 256) {
      uint32_t v = dbits[i];
      bool match = (shift == 24) || ((v >> (shift + 8)) == prefix);
      if (match) atomicAdd(&hist[(v >> shift) & 255], 1u);
    }
    __syncthreads();
    uint32_t myh = hist[tid];
    // intra-wave inclusive scan (no barriers)
    uint32_t v = myh;
#pragma unroll
    for (int off = 1; off < 64; off <<= 1) {
      uint32_t o = __shfl_up(v, off, 64);
      if (lane >= off) v += o;
    }
    if (lane == 63) wsum[wv] = v;
    __syncthreads();
    uint32_t base = 0;
#pragma unroll
    for (int w = 0; w < 4; ++w) base += (w < wv) ? wsum[w] : 0u;
    uint32_t cum = v + base;
    uint32_t prev = cum - myh;
    if (prev < want && want <= cum) { svDigit = (uint32_t)tid; svWant = want - prev; }
    __syncthreads();
    prefix = (prefix << 8) | svDigit;
    want = svWant;
  }
  uint32_t tval = prefix;
  if (tid == 0) { svClt = 0; svCeq = 0; }
  __syncthreads();
  for (int i = tid; i < Nn; i += 256) {
    if (dbits[i] < tval) { uint32_t pos = atomicAdd(&svClt, 1u); sel[pos] = i; }
  }
  __syncthreads();
  uint32_t clt = svClt;
  for (int i = tid; i < Nn; i += 256) {
    if (dbits[i] == tval) {
      uint32_t pos = atomicAdd(&svCeq, 1u);
      if (clt + pos < 64) sel[clt + pos] = i;
    }
  }
  __syncthreads();
  if (tid < 192) {
    int k = tid / 3, c = tid - k * 3;
    float sub = (c == 0) ? px : (c == 1) ? py : pz;
    gxyz[(size_t)bp * 192 + tid] = xyz[(size_t)(b * Nn + sel[k]) * 3 + c] - sub;
  }
  int dch = tid & 127, half = tid >> 7;
  float m = -1e30f;
  for (int k = half * 32; k < half * 32 + 32; ++k)
    m = fmaxf(m, feat[(size_t)(b * Nn + sel[k]) * Dd + dch]);
  red[tid] = m;
  __syncthreads();
  if (half == 0) pfb[(size_t)bp * Dd + dch] = f2bf(fmaxf(m, red[tid + 128]));
}

// ---------------- bf16 MFMA GEMM: C[M,N] = A[M,K] * Bt[N,K]^T ----------------
template <int EPI>
__global__ __launch_bounds__(256)
void gemm_bt(const unsigned short* __restrict__ A, const unsigned short* __restrict__ Bt,
             float* __restrict__ Cf, unsigned short* __restrict__ Ch,
             const float* __restrict__ p0,
             int Npar, int Kd, int nbn) {
  __shared__ __align__(16) unsigned short As[128 * 32];
  __shared__ __align__(16) unsigned short Bs[128 * 32];
  const int tid = threadIdx.x;
  const int lane = tid & 63, wid = tid >> 6;
  const int bn = blockIdx.x % nbn, bm = blockIdx.x / nbn;
  const int m0 = bm * 128, n0 = bn * 128;
  const int quad = lane >> 4, l15 = lane & 15;
  const int wm = wid & 1, wn = wid >> 1;

  floatx4 acc[4][4];
#pragma unroll
  for (int i = 0; i < 4; ++i)
#pragma unroll
    for (int j = 0; j < 4; ++j) acc[i][j] = floatx4{0.f, 0.f, 0.f, 0.f};

  const int c0i = tid, c1i = tid + 256;
  const int r0 = c0i >> 2, o0 = (c0i & 3) * 8;
  const int r1 = c1i >> 2, o1 = (c1i & 3) * 8;

  for (int k0 = 0; k0 < Kd; k0 += 32) {
    async_copy16(A + (size_t)(m0 + r0) * Kd + k0 + o0, &As[c0i * 8]);
    async_copy16(A + (size_t)(m0 + r1) * Kd + k0 + o1, &As[c1i * 8]);
    async_copy16(Bt + (size_t)(n0 + r0) * Kd + k0 + o0, &Bs[c0i * 8]);
    async_copy16(Bt + (size_t)(n0 + r1) * Kd + k0 + o1, &Bs[c1i * 8]);
    __syncthreads();
    const bf16x8* Ap = reinterpret_cast<const bf16x8*>(As);
    const bf16x8* Bp = reinterpret_cast<const bf16x8*>(Bs);
    bf16x8 af[4], bfv[4];
#pragma unroll
    for (int t = 0; t < 4; ++t) {
      af[t]  = Ap[(wm * 64 + t * 16 + l15) * 4 + quad];
      bfv[t] = Bp[(wn * 64 + t * 16 + l15) * 4 + quad];
    }
#pragma unroll
    for (int mt = 0; mt < 4; ++mt)
#pragma unroll
      for (int nt = 0; nt < 4; ++nt)
        acc[mt][nt] = __builtin_amdgcn_mfma_f32_16x16x32_bf16(af[mt], bfv[nt], acc[mt][nt], 0, 0, 0);
    __syncthreads();
  }

  const int rowBase = m0 + wm * 64 + quad * 4;
  const int colBase = n0 + wn * 64 + l15;

  if (EPI == 0) {
#pragma unroll
    for (int mt = 0; mt < 4; ++mt)
#pragma unroll
      for (int nt = 0; nt < 4; ++nt)
#pragma unroll
        for (int r = 0; r < 4; ++r)
          Cf[(size_t)(rowBase + mt * 16 + r) * Npar + colBase + nt * 16] = acc[mt][nt][r];
  } else {
#pragma unroll
    for (int nt = 0; nt < 4; ++nt) {
      float bias = p0[colBase + nt * 16];
#pragma unroll
      for (int mt = 0; mt < 4; ++mt)
#pragma unroll
        for (int r = 0; r < 4; ++r) {
          float v = fmaxf(acc[mt][nt][r] + bias, 0.f);
          Ch[(size_t)(rowBase + mt * 16 + r) * Npar + colBase + nt * 16] = f2bf(v);
        }
    }
  }
}

// ---------------- merged u1 + hb GEMM (both read pfb only; K=128) ----------------
// blocks 0..127: u1 = pf @ cw1t (fp32 store). blocks 128..255: hb = relu(pf@w1t+b1).
__global__ __launch_bounds__(256)
void gemm_bt01(const unsigned short* __restrict__ A,
               const unsigned short* __restrict__ Bt0,   // cw1t
               const unsigned short* __restrict__ Bt1,   // w1t
               float* __restrict__ Cf, unsigned short* __restrict__ Ch,
               const float* __restrict__ p0) {
  __shared__ __align__(16) unsigned short As[128 * 32];
  __shared__ __align__(16) unsigned short Bs[128 * 32];
  const int tid = threadIdx.x;
  const int lane = tid & 63, wid = tid >> 6;
  const bool second = blockIdx.x >= 128;
  const int blk = blockIdx.x & 127;
  const unsigned short* Bt = second ? Bt1 : Bt0;
  const int bn = blk % 8, bm = blk / 8;
  const int m0 = bm * 128, n0 = bn * 128;
  const int quad = lane >> 4, l15 = lane & 15;
  const int wm = wid & 1, wn = wid >> 1;
  const int Kd = 128;

  floatx4 acc[4][4];
#pragma unroll
  for (int i = 0; i < 4; ++i)
#pragma unroll
    for (int j = 0; j < 4; ++j) acc[i][j] = floatx4{0.f, 0.f, 0.f, 0.f};

  const int c0i = tid, c1i = tid + 256;
  const int r0 = c0i >> 2, o0 = (c0i & 3) * 8;
  const int r1 = c1i >> 2, o1 = (c1i & 3) * 8;

  for (int k0 = 0; k0 < Kd; k0 += 32) {
    async_copy16(A + (size_t)(m0 + r0) * Kd + k0 + o0, &As[c0i * 8]);
    async_copy16(A + (size_t)(m0 + r1) * Kd + k0 + o1, &As[c1i * 8]);
    async_copy16(Bt + (size_t)(n0 + r0) * Kd + k0 + o0, &Bs[c0i * 8]);
    async_copy16(Bt + (size_t)(n0 + r1) * Kd + k0 + o1, &Bs[c1i * 8]);
    __syncthreads();
    const bf16x8* Ap = reinterpret_cast<const bf16x8*>(As);
    const bf16x8* Bp = reinterpret_cast<const bf16x8*>(Bs);
    bf16x8 af[4], bfv[4];
#pragma unroll
    for (int t = 0; t < 4; ++t) {
      af[t]  = Ap[(wm * 64 + t * 16 + l15) * 4 + quad];
      bfv[t] = Bp[(wn * 64 + t * 16 + l15) * 4 + quad];
    }
#pragma unroll
    for (int mt = 0; mt < 4; ++mt)
#pragma unroll
      for (int nt = 0; nt < 4; ++nt)
        acc[mt][nt] = __builtin_amdgcn_mfma_f32_16x16x32_bf16(af[mt], bfv[nt], acc[mt][nt], 0, 0, 0);
    __syncthreads();
  }

  const int rowBase = m0 + wm * 64 + quad * 4;
  const int colBase = n0 + wn * 64 + l15;

  if (!second) {
#pragma unroll
    for (int mt = 0; mt < 4; ++mt)
#pragma unroll
      for (int nt = 0; nt < 4; ++nt)
#pragma unroll
        for (int r = 0; r < 4; ++r)
          Cf[(size_t)(rowBase + mt * 16 + r) * 1024 + colBase + nt * 16] = acc[mt][nt][r];
  } else {
#pragma unroll
    for (int nt = 0; nt < 4; ++nt) {
      float bias = p0[colBase + nt * 16];
#pragma unroll
      for (int mt = 0; mt < 4; ++mt)
#pragma unroll
        for (int r = 0; r < 4; ++r) {
          float v = fmaxf(acc[mt][nt][r] + bias, 0.f);
          Ch[(size_t)(rowBase + mt * 16 + r) * 1024 + colBase + nt * 16] = f2bf(v);
        }
    }
  }
}

// ---------------- conv2 MX-fp8 (R12): bn-loop inside, direct fine store ----------------
__global__ __launch_bounds__(256)
void gemm_mx3b(const uint8_t* __restrict__ A, const uint8_t* __restrict__ Bt,
               const float* __restrict__ p0, const float* __restrict__ p1,
               const float* __restrict__ cw3, const float* __restrict__ coarse,
               const float* __restrict__ cb3, float* __restrict__ fine,
               int rowOff, int Kd) {
  __shared__ __align__(128) uint8_t As[128 * 128];
  __shared__ __align__(128) uint8_t Bs[128 * 128];
  __shared__ float fsum[2][2][64][3];
  const int tid = threadIdx.x;
  const int lane = tid & 63, wid = tid >> 6;
  const int bm = blockIdx.x;
  const int m0 = bm * 128;
  const int quad = lane >> 4, l15 = lane & 15;
  const int wm = wid & 1, wn = wid >> 1;

  float fp[4][4][3];
#pragma unroll
  for (int mt = 0; mt < 4; ++mt)
#pragma unroll
    for (int r = 0; r < 4; ++r)
      fp[mt][r][0] = fp[mt][r][1] = fp[mt][r][2] = 0.f;

  for (int bn = 0; bn < 8; ++bn) {
    const int n0 = bn * 128;
    floatx4 acc[4][4];
#pragma unroll
    for (int i = 0; i < 4; ++i)
#pragma unroll
      for (int j = 0; j < 4; ++j) acc[i][j] = floatx4{0.f, 0.f, 0.f, 0.f};

    for (int k0 = 0; k0 < Kd; k0 += 128) {
#pragma unroll
      for (int c = 0; c < 4; ++c) {
        int ci = c * 256 + tid;
        int row = ci >> 3, cp = ci & 7;
        int cc = cp ^ (row & 7);
        async_copy16(A + (size_t)(m0 + row) * Kd + k0 + cc * 16, &As[ci * 16]);
        async_copy16(Bt + (size_t)(n0 + row) * Kd + k0 + cc * 16, &Bs[ci * 16]);
      }
      __syncthreads();
      const uint4* Ap = (const uint4*)As;
      const uint4* Bp = (const uint4*)Bs;
      int32x8 av[4], bv[4];
#pragma unroll
      for (int t = 0; t < 4; ++t) {
        int rm = wm * 64 + t * 16 + l15;
        int rn = wn * 64 + t * 16 + l15;
        int swm = rm & 7, swn = rn & 7;
        uint4 alo = Ap[rm * 8 + ((2 * quad) ^ swm)];
        uint4 ahi = Ap[rm * 8 + ((2 * quad + 1) ^ swm)];
        uint4 blo = Bp[rn * 8 + ((2 * quad) ^ swn)];
        uint4 bhi = Bp[rn * 8 + ((2 * quad + 1) ^ swn)];
        av[t] = int32x8{(int)alo.x, (int)alo.y, (int)alo.z, (int)alo.w,
                        (int)ahi.x, (int)ahi.y, (int)ahi.z, (int)ahi.w};
        bv[t] = int32x8{(int)blo.x, (int)blo.y, (int)blo.z, (int)blo.w,
                        (int)bhi.x, (int)bhi.y, (int)bhi.z, (int)bhi.w};
      }
#pragma unroll
      for (int mt = 0; mt < 4; ++mt)
#pragma unroll
        for (int nt = 0; nt < 4; ++nt)
          acc[mt][nt] = __builtin_amdgcn_mfma_scale_f32_16x16x128_f8f6f4(
              av[mt], bv[nt], acc[mt][nt], 0, 0, 0, 127, 0, 127);
      __syncthreads();
    }

    const int colBase = n0 + wn * 64 + l15;
#pragma unroll
    for (int nt = 0; nt < 4; ++nt) {
      int col = colBase + nt * 16;
      float sc = p0[col], sh = p1[col];
      float c0 = cw3[col * 3], c1 = cw3[col * 3 + 1], c2 = cw3[col * 3 + 2];
#pragma unroll
      for (int mt = 0; mt < 4; ++mt)
#pragma unroll
        for (int r = 0; r < 4; ++r) {
          float v = fmaxf(acc[mt][nt][r] * sc + sh, 0.f);
          fp[mt][r][0] += v * c0; fp[mt][r][1] += v * c1; fp[mt][r][2] += v * c2;
        }
    }
  }

#pragma unroll
  for (int off = 1; off < 16; off <<= 1)
#pragma unroll
    for (int mt = 0; mt < 4; ++mt)
#pragma unroll
      for (int r = 0; r < 4; ++r)
#pragma unroll
        for (int i = 0; i < 3; ++i)
          fp[mt][r][i] += __shfl_xor(fp[mt][r][i], off, 64);
  if (l15 == 0) {
#pragma unroll
    for (int mt = 0; mt < 4; ++mt)
#pragma unroll
      for (int r = 0; r < 4; ++r) {
        int rowLocal = quad * 4 + mt * 16 + r;
#pragma unroll
        for (int i = 0; i < 3; ++i) fsum[wm][wn][rowLocal][i] = fp[mt][r][i];
      }
  }
  __syncthreads();
  for (int t = tid; t < 128 * 3; t += 256) {
    int row = t / 3, i = t - row * 3;
    float s = fsum[row >> 6][0][row & 63][i] + fsum[row >> 6][1][row & 63][i];
    int g = rowOff + m0 + row;
    int bp = g >> 6, kp = g & 63, j = kp >> 2;
    fine[(size_t)g * 3 + i] = s + cb3[i] + coarse[(size_t)bp * 48 + j * 3 + i];
  }
}

// ---------------- coarse = h2m @ w3 + b3 (fp32, thin N=48) ----------------
__global__ __launch_bounds__(256)
void coarse_k(const unsigned short* __restrict__ h2m, const float* __restrict__ w3,
              const float* __restrict__ b3, float* __restrict__ coarse) {
  int r = blockIdx.x, tid = threadIdx.x;
  __shared__ float hrow[1024];
  __shared__ float part[192];
  for (int i = tid; i < 1024; i += 256) hrow[i] = bf2f(h2m[(size_t)r * 1024 + i]);
  __syncthreads();
  if (tid < 192) {
    int j = tid % 48, seg = tid / 48;
    float acc = 0.f;
    for (int k = seg * 256; k < seg * 256 + 256; ++k) acc += hrow[k] * w3[(size_t)k * 48 + j];
    part[tid] = acc;
  }
  __syncthreads();
  if (tid < 48)
    coarse[(size_t)r * 48 + tid] = part[tid] + part[tid + 48] + part[tid + 96] + part[tid + 144] + b3[tid];
}

// ---------------- h1 = relu(bn1(...)) -> fp8 e4m3 ----------------
__global__ __launch_bounds__(256)
void h1build_k(const float* __restrict__ u1, const float* __restrict__ cw1,
               const float* __restrict__ coarse, const float* __restrict__ sc1,
               const float* __restrict__ sh1, uint8_t* __restrict__ h1) {
  int bp = blockIdx.x, tid = threadIdx.x;
  __shared__ float co[48];
  if (tid < 48) co[tid] = coarse[(size_t)bp * 48 + tid];
  __syncthreads();
  int n0 = tid * 4;
  float4 un  = *(const float4*)&u1[(size_t)bp * 1024 + n0];
  float4 a0  = *(const float4*)&cw1[128 * 1024 + n0];
  float4 a1  = *(const float4*)&cw1[129 * 1024 + n0];
  float4 b0  = *(const float4*)&cw1[130 * 1024 + n0];
  float4 b1v = *(const float4*)&cw1[131 * 1024 + n0];
  float4 b2v = *(const float4*)&cw1[132 * 1024 + n0];
  float4 sc  = *(const float4*)&sc1[n0];
  float4 sh  = *(const float4*)&sh1[n0];
  const float sxv[4] = {-0.05f, 0.05f, -0.05f, 0.05f};
  const float syv[4] = {-0.05f, -0.05f, 0.05f, 0.05f};
  float s[4][4];
#pragma unroll
  for (int g = 0; g < 4; ++g) {
    s[g][0] = sxv[g] * a0.x + syv[g] * a1.x;
    s[g][1] = sxv[g] * a0.y + syv[g] * a1.y;
    s[g][2] = sxv[g] * a0.z + syv[g] * a1.z;
    s[g][3] = sxv[g] * a0.w + syv[g] * a1.w;
  }
  uint32_t* out = (uint32_t*)h1;
  for (int k = 0; k < 64; ++k) {
    int j = k >> 2, g = k & 3;
    float c0 = co[j * 3], c1 = co[j * 3 + 1], c2 = co[j * 3 + 2];
    float x0 = un.x + s[g][0] + c0 * b0.x + c1 * b1v.x + c2 * b2v.x;
    float x1 = un.y + s[g][1] + c0 * b0.y + c1 * b1v.y + c2 * b2v.y;
    float x2 = un.z + s[g][2] + c0 * b0.z + c1 * b1v.z + c2 * b2v.z;
    float x3 = un.w + s[g][3] + c0 * b0.w + c1 * b1v.w + c2 * b2v.w;
    float v0 = fmaxf(x0 * sc.x + sh.x, 0.f);
    float v1 = fmaxf(x1 * sc.y + sh.y, 0.f);
    float v2 = fmaxf(x2 * sc.z + sh.z, 0.f);
    float v3 = fmaxf(x3 * sc.w + sh.w, 0.f);
    int w = __builtin_amdgcn_cvt_pk_fp8_f32(v0, v1, 0, false);
    w = __builtin_amdgcn_cvt_pk_fp8_f32(v2, v3, w, true);
    out[(size_t)(bp * 64 + k) * 256 + tid] = (uint32_t)w;
  }
}

// ---------------- chamfer: one wave per patch ----------------
__global__ __launch_bounds__(256)
void chamfer_k(const float* __restrict__ fine, const float* __restrict__ gxyz,
               float* __restrict__ out) {
  int tid = threadIdx.x, wv = tid >> 6, lane = tid & 63;
  int bp = blockIdx.x * 4 + wv;
  __shared__ float sf[4][64][3], sg[4][64][3];
  const float* fr = &fine[(size_t)(bp * 64 + lane) * 3];
  const float* gr = &gxyz[(size_t)(bp * 64 + lane) * 3];
  sf[wv][lane][0] = fr[0]; sf[wv][lane][1] = fr[1]; sf[wv][lane][2] = fr[2];
  sg[wv][lane][0] = gr[0]; sg[wv][lane][1] = gr[1]; sg[wv][lane][2] = gr[2];
  __syncthreads();
  float f0 = sf[wv][lane][0], f1 = sf[wv][lane][1], f2 = sf[wv][lane][2];
  float g0 = sg[wv][lane][0], g1 = sg[wv][lane][1], g2 = sg[wv][lane][2];
  float rmin = 1e30f, cmin = 1e30f;
  for (int j = 0; j < 64; ++j) {
    float dx = f0 - sg[wv][j][0], dy = f1 - sg[wv][j][1], dz = f2 - sg[wv][j][2];
    rmin = fminf(rmin, dx * dx + dy * dy + dz * dz);
    float ex = sf[wv][j][0] - g0, ey = sf[wv][j][1] - g1, ez = sf[wv][j][2] - g2;
    cmin = fminf(cmin, ex * ex + ey * ey + ez * ez);
  }
  float tot = rmin + cmin;
  for (int off = 32; off; off >>= 1) tot += __shfl_down(tot, off, 64);
  if (lane == 0) atomicAdd(out, tot * (1.0f / 131072.0f));
}

extern "C" void kernel_launch(void* const* d_in, const int* in_sizes, int n_in,
                              void* d_out, int out_size, void* d_ws, size_t ws_size,
                              hipStream_t stream) {
  (void)in_sizes; (void)n_in; (void)out_size;
  const float* xyz = (const float*)d_in[0];
  const float* feat = (const float*)d_in[1];
  const float* w1 = (const float*)d_in[2];
  const float* b1 = (const float*)d_in[3];
  const float* w2 = (const float*)d_in[4];
  const float* b2 = (const float*)d_in[5];
  const float* w3 = (const float*)d_in[6];
  const float* b3 = (const float*)d_in[7];
  const float* cw1 = (const float*)d_in[8];
  const float* cb1 = (const float*)d_in[9];
  const float* g1 = (const float*)d_in[10];
  const float* be1 = (const float*)d_in[11];
  const float* m1 = (const float*)d_in[12];
  const float* v1 = (const float*)d_in[13];
  const float* cw2 = (const float*)d_in[14];
  const float* cb2 = (const float*)d_in[15];
  const float* g2 = (const float*)d_in[16];
  const float* be2 = (const float*)d_in[17];
  const float* m2 = (const float*)d_in[18];
  const float* v2 = (const float*)d_in[19];
  const float* cw3 = (const float*)d_in[20];
  const float* cb3 = (const float*)d_in[21];
  float* out = (float*)d_out;

  uint8_t* ws = (uint8_t*)d_ws;
  size_t off = 0;
  auto alloc = [&](size_t bytes) {
    void* p = ws + off;
    off = (off + bytes + 255) & ~(size_t)255;
    return p;
  };
  float*          pxyz  = (float*)alloc((size_t)BP * 3 * 4);
  unsigned short* w1t   = (unsigned short*)alloc((size_t)1024 * 128 * 2);
  unsigned short* cw1t  = (unsigned short*)alloc((size_t)1024 * 128 * 2);
  unsigned short* w2t   = (unsigned short*)alloc((size_t)1024 * 1024 * 2);
  uint8_t*        cw2t8 = (uint8_t*)alloc((size_t)1024 * 1024);
  float*          sc1   = (float*)alloc(4096);
  float*          sh1   = (float*)alloc(4096);
  float*          sc2   = (float*)alloc(4096);
  float*          sh2   = (float*)alloc(4096);
  unsigned short* pfb   = (unsigned short*)alloc((size_t)BP * 128 * 2);
  float*          gxyz  = (float*)alloc((size_t)BP * 64 * 3 * 4);
  float*          u1    = (float*)alloc((size_t)BP * 1024 * 4);
  unsigned short* hb    = (unsigned short*)alloc((size_t)BP * 1024 * 2);
  unsigned short* h2m   = (unsigned short*)alloc((size_t)BP * 1024 * 2);
  float*          coarse = (float*)alloc((size_t)BP * 48 * 4);
  float*          fine  = (float*)alloc((size_t)M2 * 3 * 4);

  // ws-adaptive h1 chunking: 64 KB per patch (fp8); largest pow2 patch count that fits.
  size_t perPatch = (size_t)Kk * 1024;
  size_t avail = (ws_size > off) ? (ws_size - off - 256) : 0;
  int ppc = 2;
  while (ppc < BP && (size_t)(ppc * 2) * perPatch <= avail) ppc *= 2;
  uint8_t* h1 = (uint8_t*)alloc((size_t)ppc * perPatch);
  int nch = BP / ppc;

  // heterogeneous prologue: fps + prep + all 4 transposes in one launch
  setup_k<<<2313, 256, 0, stream>>>(xyz, pxyz,
                                    g1, be1, m1, v1, cb1, g2, be2, m2, v2, cb2,
                                    sc1, sh1, sc2, sh2, out,
                                    w1, w1t, cw1, cw1t, w2, w2t, cw2, cw2t8);
  group_k<<<BP, 256, 0, stream>>>(xyz, feat, pxyz, pfb, gxyz);
  // merged: u1 = pf @ cw1[:128] (fp32) AND hb = relu(pf @ w1 + b1)
  gemm_bt01<<<256, 256, 0, stream>>>(pfb, cw1t, w1t, u1, hb, b1);
  // h2m = relu(h @ w2 + b2)
  gemm_bt<1><<<(2048 / 128) * 8, 256, 0, stream>>>(hb, w2t, nullptr, h2m, b2,
                                                   1024, 1024, 8);
  coarse_k<<<2048, 256, 0, stream>>>(h2m, w3, b3, coarse);
  // conv2 MX-fp8, bn-loop in-block (+fused BN/ReLU + conv3 + fine store), chunked
  for (int c = 0; c < nch; ++c) {
    int pstart = c * ppc;
    int nbm = ppc * Kk / 128;
    h1build_k<<<ppc, 256, 0, stream>>>(u1 + (size_t)pstart * 1024, cw1,
                                       coarse + (size_t)pstart * 48, sc1, sh1, h1);
    gemm_mx3b<<<nbm, 256, 0, stream>>>(
        h1, cw2t8, sc2, sh2, cw3, coarse, cb3, fine, pstart * Kk, 1024);
  }
  chamfer_k<<<BP / 4, 256, 0, stream>>>(fine, gxyz, out);
}